// Round 1
// baseline (634.761 us; speedup 1.0000x reference)
//
#include <hip/hip_runtime.h>
#include <math.h>

// ---------------------------------------------------------------------------
// SharedAttentionProcessor: B=4, S=1024, C=1280, H=20, hd=64
// bf16 MFMA pipeline:
//   convert -> QKV gemm -> adain(stats+apply) -> V transpose -> flash attn
//   -> out gemm (+bias, fp32 out)
// ---------------------------------------------------------------------------

typedef __bf16 bf16x8 __attribute__((ext_vector_type(8)));
typedef float f32x4 __attribute__((ext_vector_type(4)));
typedef unsigned short u16x8 __attribute__((ext_vector_type(8)));

#define BDIM 256

__device__ inline unsigned short f2bf(float f) {
  unsigned int u = __float_as_uint(f);
  u += 0x7fffu + ((u >> 16) & 1u);   // RNE (inputs finite)
  return (unsigned short)(u >> 16);
}
__device__ inline float bf2f(unsigned short h) {
  return __uint_as_float(((unsigned int)h) << 16);
}

__device__ inline void gl_lds16(const unsigned short* g, unsigned short* l) {
  __builtin_amdgcn_global_load_lds(
      (const __attribute__((address_space(1))) unsigned int*)g,
      (__attribute__((address_space(3))) unsigned int*)l, 16, 0, 0);
}

// --------------------------- fp32 -> bf16 convert ---------------------------
__global__ __launch_bounds__(BDIM) void k_f32_to_bf16(
    const float* __restrict__ src, unsigned short* __restrict__ dst, int n4) {
  int i = blockIdx.x * BDIM + threadIdx.x;
  if (i >= n4) return;
  const float4 v = ((const float4*)src)[i];
  ushort4 o;
  o.x = f2bf(v.x); o.y = f2bf(v.y); o.z = f2bf(v.z); o.w = f2bf(v.w);
  ((ushort4*)dst)[i] = o;
}

// --------------------------- bf16 GEMM (m93/m97 style) ----------------------
// A [M,K] row-major bf16, B [N,K] row-major bf16 (i.e. computes A @ B^T).
// Writes bf16 (Cbf) or fp32+bias (Cf). 128x128 tile, BK=32, 256 thr = 4 waves.
__global__ __launch_bounds__(BDIM) void k_gemm_bf16(
    const unsigned short* __restrict__ A, const unsigned short* __restrict__ B,
    unsigned short* __restrict__ Cbf, float* __restrict__ Cf,
    const float* __restrict__ bias, int M, int N, int K) {
  __shared__ unsigned short As[128 * 32];
  __shared__ unsigned short Bs[128 * 32];
  const int t = threadIdx.x;
  const int w = t >> 6, lane = t & 63, quad = lane >> 4, l16 = lane & 15;
  const int wm = (w >> 1) << 6, wn = (w & 1) << 6;
  const int mBase = blockIdx.x * 128, nBase = blockIdx.y * 128;

  f32x4 acc[4][4];
#pragma unroll
  for (int i = 0; i < 4; i++)
#pragma unroll
    for (int j = 0; j < 4; j++) acc[i][j] = (f32x4){0.f, 0.f, 0.f, 0.f};

  const int r0 = t >> 2;             // 0..63
  const int kk0 = (t & 3) * 8;       // 0,8,16,24

  for (int k0 = 0; k0 < K; k0 += 32) {
    gl_lds16(A + (size_t)(mBase + r0) * K + k0 + kk0, As + t * 8);
    gl_lds16(A + (size_t)(mBase + 64 + r0) * K + k0 + kk0, As + (t + 256) * 8);
    gl_lds16(B + (size_t)(nBase + r0) * K + k0 + kk0, Bs + t * 8);
    gl_lds16(B + (size_t)(nBase + 64 + r0) * K + k0 + kk0, Bs + (t + 256) * 8);
    __syncthreads();
    bf16x8 af[4], bfr[4];
#pragma unroll
    for (int i = 0; i < 4; i++)
      af[i] = *(const bf16x8*)(As + (wm + i * 16 + l16) * 32 + quad * 8);
#pragma unroll
    for (int i = 0; i < 4; i++)
      bfr[i] = *(const bf16x8*)(Bs + (wn + i * 16 + l16) * 32 + quad * 8);
#pragma unroll
    for (int mi = 0; mi < 4; mi++)
#pragma unroll
      for (int ni = 0; ni < 4; ni++)
        acc[mi][ni] = __builtin_amdgcn_mfma_f32_16x16x32_bf16(
            af[mi], bfr[ni], acc[mi][ni], 0, 0, 0);
    __syncthreads();
  }

#pragma unroll
  for (int mi = 0; mi < 4; mi++) {
#pragma unroll
    for (int r = 0; r < 4; r++) {
      const int row = mBase + wm + mi * 16 + quad * 4 + r;
#pragma unroll
      for (int ni = 0; ni < 4; ni++) {
        const int col = nBase + wn + ni * 16 + l16;
        const float v = acc[mi][ni][r];
        if (Cf) Cf[(size_t)row * N + col] = v + (bias ? bias[col] : 0.f);
        else Cbf[(size_t)row * N + col] = f2bf(v);
      }
    }
  }
}

// --------------------------- adain stats ------------------------------------
// QKV [4096, 3840] bf16; stats layout: [(which*2+{mean,std})*4 + b]*1280 + c
__global__ __launch_bounds__(BDIM) void k_stats(
    const unsigned short* __restrict__ QKV, float* __restrict__ stats) {
  const int cg = blockIdx.x, which = blockIdx.y, b = blockIdx.z;
  const int c = cg * 256 + threadIdx.x;
  const size_t base = (size_t)(b * 1024) * 3840 + which * 1280 + c;
  float s = 0.f, s2 = 0.f;
  for (int i = 0; i < 1024; ++i) {
    const float x = bf2f(QKV[base + (size_t)i * 3840]);
    s += x;
    s2 = fmaf(x, x, s2);
  }
  const float mean = s * (1.0f / 1024.0f);
  const float var = (s2 - 1024.0f * mean * mean) * (1.0f / 1023.0f);
  stats[((which * 2 + 0) * 4 + b) * 1280 + c] = mean;
  stats[((which * 2 + 1) * 4 + b) * 1280 + c] = sqrtf(var + 1e-5f);
}

// --------------------------- adain apply ------------------------------------
__global__ __launch_bounds__(BDIM) void k_adain(
    const unsigned short* __restrict__ QKV, const float* __restrict__ stats,
    unsigned short* __restrict__ qn, unsigned short* __restrict__ kn) {
  const int which = blockIdx.z, b = blockIdx.y;
  const int s = blockIdx.x / 5, cg = blockIdx.x % 5;
  const int c = cg * 256 + threadIdx.x;
  const int sb = (b < 2) ? 0 : 2;  // style batch
  const float x = bf2f(QKV[((size_t)(b * 1024 + s)) * 3840 + which * 1280 + c]);
  const float mean = stats[((which * 2 + 0) * 4 + b) * 1280 + c];
  const float stdv = stats[((which * 2 + 1) * 4 + b) * 1280 + c];
  const float meanS = stats[((which * 2 + 0) * 4 + sb) * 1280 + c];
  const float stdS = stats[((which * 2 + 1) * 4 + sb) * 1280 + c];
  const float y = (x - mean) / stdv * stdS + meanS;
  unsigned short* dst = (which == 0) ? qn : kn;
  dst[((size_t)(b * 1024 + s)) * 1280 + c] = f2bf(y);
}

// --------------------------- V transpose ------------------------------------
// QKV v-part [b, s, c] -> vt [b, c, s]   (so PV B-operand is contiguous in s)
__global__ __launch_bounds__(BDIM) void k_transpose_v(
    const unsigned short* __restrict__ QKV, unsigned short* __restrict__ vt) {
  __shared__ unsigned short tile[64][65];
  const int s0 = blockIdx.x * 64, c0 = blockIdx.y * 64, b = blockIdx.z;
  const int t = threadIdx.x;
  const int r = t >> 2, seg = (t & 3) * 16;
  const size_t goff = ((size_t)(b * 1024 + s0 + r)) * 3840 + 2560 + c0 + seg;
  const u16x8 va = *(const u16x8*)(QKV + goff);
  const u16x8 vb = *(const u16x8*)(QKV + goff + 8);
#pragma unroll
  for (int j = 0; j < 8; j++) {
    tile[r][seg + j] = va[j];
    tile[r][seg + 8 + j] = vb[j];
  }
  __syncthreads();
  u16x8 o0, o1;
#pragma unroll
  for (int j = 0; j < 8; j++) {
    o0[j] = tile[seg + j][r];
    o1[j] = tile[seg + 8 + j][r];
  }
  const size_t ooff = ((size_t)(b * 1280 + c0 + r)) * 1024 + s0 + seg;
  *(u16x8*)(vt + ooff) = o0;
  *(u16x8*)(vt + ooff + 8) = o1;
}

// --------------------------- flash attention --------------------------------
// grid (qtile=16, h=20, b=4), 256 thr = 4 waves; wave handles 16 query rows.
// Keys/values: 0..1023 from batch b, 1024..2047 from style batch (+log2 bias).
__global__ __launch_bounds__(BDIM) void k_attn(
    const unsigned short* __restrict__ qn, const unsigned short* __restrict__ kn,
    const unsigned short* __restrict__ vt, unsigned short* __restrict__ out) {
  const int S = 1024, C = 1280;
  const int qt = blockIdx.x, h = blockIdx.y, b = blockIdx.z;
  const int t = threadIdx.x, w = t >> 6, lane = t & 63;
  const int quad = lane >> 4, l16 = lane & 15;
  const int bstyle = (b < 2) ? 0 : 2;
  const int qrow = qt * 64 + w * 16;

  __shared__ unsigned short Plds[4][16][72];  // 72: 144B rows, 16B-aligned

  const size_t qoff = ((size_t)(b * S + qrow + l16)) * C + h * 64 + quad * 8;
  const bf16x8 aq0 = *(const bf16x8*)(qn + qoff);
  const bf16x8 aq1 = *(const bf16x8*)(qn + qoff + 32);

  f32x4 o[4];
  float m_i[4], l_i[4];
#pragma unroll
  for (int i = 0; i < 4; i++) {
    o[i] = (f32x4){0.f, 0.f, 0.f, 0.f};
    m_i[i] = -INFINITY;
    l_i[i] = 0.f;
  }

  for (int kt = 0; kt < 32; ++kt) {
    const int kb = kt * 64;
    const int bs = (kb < S) ? b : bstyle;
    const int sk = kb & (S - 1);
    const float bias = (kb >= S) ? 0.6931471805599453f : 0.0f;

    f32x4 sacc[4];
#pragma unroll
    for (int nt = 0; nt < 4; ++nt) {
      const size_t koff =
          ((size_t)(bs * S + sk + nt * 16 + l16)) * C + h * 64 + quad * 8;
      const bf16x8 bk0 = *(const bf16x8*)(kn + koff);
      const bf16x8 bk1 = *(const bf16x8*)(kn + koff + 32);
      f32x4 z = (f32x4){0.f, 0.f, 0.f, 0.f};
      z = __builtin_amdgcn_mfma_f32_16x16x32_bf16(aq0, bk0, z, 0, 0, 0);
      z = __builtin_amdgcn_mfma_f32_16x16x32_bf16(aq1, bk1, z, 0, 0, 0);
      sacc[nt] = z;
    }

    float p[4][4], alpha[4];
#pragma unroll
    for (int r = 0; r < 4; r++) {
      float mx = -INFINITY;
#pragma unroll
      for (int nt = 0; nt < 4; nt++) {
        const float sv = sacc[nt][r] * 0.125f + bias;
        p[nt][r] = sv;
        mx = fmaxf(mx, sv);
      }
#pragma unroll
      for (int msk = 1; msk < 16; msk <<= 1)
        mx = fmaxf(mx, __shfl_xor(mx, msk, 64));
      const float mnew = fmaxf(m_i[r], mx);
      alpha[r] = __expf(m_i[r] - mnew);
      float sum = 0.f;
#pragma unroll
      for (int nt = 0; nt < 4; nt++) {
        const float e = __expf(p[nt][r] - mnew);
        p[nt][r] = e;
        sum += e;
      }
#pragma unroll
      for (int msk = 1; msk < 16; msk <<= 1) sum += __shfl_xor(sum, msk, 64);
      l_i[r] = l_i[r] * alpha[r] + sum;
      m_i[r] = mnew;
    }
#pragma unroll
    for (int dt = 0; dt < 4; dt++)
#pragma unroll
      for (int r = 0; r < 4; r++) o[dt][r] *= alpha[r];

    // P: C-layout -> LDS -> A-layout (per-wave, no barrier needed)
#pragma unroll
    for (int nt = 0; nt < 4; nt++)
#pragma unroll
      for (int r = 0; r < 4; r++)
        Plds[w][quad * 4 + r][l16 + nt * 16] = f2bf(p[nt][r]);

    const bf16x8 pa0 = *(const bf16x8*)&Plds[w][l16][quad * 8];
    const bf16x8 pa1 = *(const bf16x8*)&Plds[w][l16][32 + quad * 8];

#pragma unroll
    for (int dt = 0; dt < 4; ++dt) {
      const size_t voff =
          ((size_t)(bs * C) + h * 64 + dt * 16 + l16) * (size_t)S + sk + quad * 8;
      const bf16x8 vb0 = *(const bf16x8*)(vt + voff);
      const bf16x8 vb1 = *(const bf16x8*)(vt + voff + 32);
      o[dt] = __builtin_amdgcn_mfma_f32_16x16x32_bf16(pa0, vb0, o[dt], 0, 0, 0);
      o[dt] = __builtin_amdgcn_mfma_f32_16x16x32_bf16(pa1, vb1, o[dt], 0, 0, 0);
    }
  }

#pragma unroll
  for (int dt = 0; dt < 4; ++dt)
#pragma unroll
    for (int r = 0; r < 4; r++) {
      const int row = qrow + quad * 4 + r;
      out[((size_t)(b * S + row)) * C + h * 64 + dt * 16 + l16] =
          f2bf(o[dt][r] / l_i[r]);
    }
}

// ---------------------------------------------------------------------------
extern "C" void kernel_launch(void* const* d_in, const int* in_sizes, int n_in,
                              void* d_out, int out_size, void* d_ws,
                              size_t ws_size, hipStream_t stream) {
  const float* X = (const float*)d_in[0];
  const float* Wq = (const float*)d_in[1];
  const float* Wk = (const float*)d_in[2];
  const float* Wv = (const float*)d_in[3];
  const float* Wo = (const float*)d_in[4];
  const float* bo = (const float*)d_in[5];
  float* out = (float*)d_out;

  char* ws = (char*)d_ws;
  size_t off = 0;
  auto alloc = [&](size_t bytes) {
    char* p = ws + off;
    off += (bytes + 255) & ~(size_t)255;
    return p;
  };
  unsigned short* Xbf = (unsigned short*)alloc(4096ull * 1280 * 2);
  unsigned short* Wcat = (unsigned short*)alloc(3840ull * 1280 * 2);
  unsigned short* Wobf = (unsigned short*)alloc(1280ull * 1280 * 2);
  unsigned short* QKV = (unsigned short*)alloc(4096ull * 3840 * 2);
  float* stats = (float*)alloc(2ull * 2 * 4 * 1280 * 4);
  unsigned short* qnb = (unsigned short*)alloc(4096ull * 1280 * 2);
  unsigned short* knb = (unsigned short*)alloc(4096ull * 1280 * 2);
  unsigned short* vtb = (unsigned short*)alloc(4096ull * 1280 * 2);
  unsigned short* attn = (unsigned short*)alloc(4096ull * 1280 * 2);

  k_f32_to_bf16<<<5120, BDIM, 0, stream>>>(X, Xbf, 4096 * 1280 / 4);
  k_f32_to_bf16<<<1600, BDIM, 0, stream>>>(Wq, Wcat, 1280 * 1280 / 4);
  k_f32_to_bf16<<<1600, BDIM, 0, stream>>>(Wk, Wcat + 1280 * 1280, 1280 * 1280 / 4);
  k_f32_to_bf16<<<1600, BDIM, 0, stream>>>(Wv, Wcat + 2 * 1280 * 1280, 1280 * 1280 / 4);
  k_f32_to_bf16<<<1600, BDIM, 0, stream>>>(Wo, Wobf, 1280 * 1280 / 4);

  k_gemm_bf16<<<dim3(32, 30), BDIM, 0, stream>>>(Xbf, Wcat, QKV, nullptr,
                                                 nullptr, 4096, 3840, 1280);
  k_stats<<<dim3(5, 2, 4), BDIM, 0, stream>>>(QKV, stats);
  k_adain<<<dim3(5120, 4, 2), BDIM, 0, stream>>>(QKV, stats, qnb, knb);
  k_transpose_v<<<dim3(16, 20, 4), BDIM, 0, stream>>>(QKV, vtb);
  k_attn<<<dim3(16, 20, 4), BDIM, 0, stream>>>(qnb, knb, vtb, attn);
  k_gemm_bf16<<<dim3(32, 10), BDIM, 0, stream>>>(attn, Wobf, nullptr, out, bo,
                                                 4096, 1280, 1280);
}

// Round 2
// 383.666 us; speedup vs baseline: 1.6545x; 1.6545x over previous
//
#include <hip/hip_runtime.h>
#include <math.h>

// ---------------------------------------------------------------------------
// SharedAttentionProcessor: B=4, S=1024, C=1280, H=20, hd=64
// bf16 MFMA pipeline:
//   convert -> QKV gemm -> adain(stats+apply) -> V transpose -> flash attn
//   -> out gemm (+bias, fp32 out)
// R2: attention rewritten — no online max (exp-sum only, softmax is
// shift-invariant and logits bounded), K/V tiles staged to LDS via
// global_load_lds (double-buffered, shared across waves).
// ---------------------------------------------------------------------------

typedef __bf16 bf16x8 __attribute__((ext_vector_type(8)));
typedef float f32x4 __attribute__((ext_vector_type(4)));
typedef unsigned short u16x8 __attribute__((ext_vector_type(8)));

#define BDIM 256

__device__ inline unsigned short f2bf(float f) {
  unsigned int u = __float_as_uint(f);
  u += 0x7fffu + ((u >> 16) & 1u);   // RNE (inputs finite)
  return (unsigned short)(u >> 16);
}
__device__ inline float bf2f(unsigned short h) {
  return __uint_as_float(((unsigned int)h) << 16);
}

__device__ inline void gl_lds16(const unsigned short* g, unsigned short* l) {
  __builtin_amdgcn_global_load_lds(
      (const __attribute__((address_space(1))) unsigned int*)g,
      (__attribute__((address_space(3))) unsigned int*)l, 16, 0, 0);
}

// --------------------------- fp32 -> bf16 convert ---------------------------
__global__ __launch_bounds__(BDIM) void k_f32_to_bf16(
    const float* __restrict__ src, unsigned short* __restrict__ dst, int n4) {
  int i = blockIdx.x * BDIM + threadIdx.x;
  if (i >= n4) return;
  const float4 v = ((const float4*)src)[i];
  ushort4 o;
  o.x = f2bf(v.x); o.y = f2bf(v.y); o.z = f2bf(v.z); o.w = f2bf(v.w);
  ((ushort4*)dst)[i] = o;
}

// --------------------------- bf16 GEMM (m93/m97 style) ----------------------
// A [M,K] row-major bf16, B [N,K] row-major bf16 (i.e. computes A @ B^T).
// Writes bf16 (Cbf) or fp32+bias (Cf). 128x128 tile, BK=32, 256 thr = 4 waves.
__global__ __launch_bounds__(BDIM) void k_gemm_bf16(
    const unsigned short* __restrict__ A, const unsigned short* __restrict__ B,
    unsigned short* __restrict__ Cbf, float* __restrict__ Cf,
    const float* __restrict__ bias, int M, int N, int K) {
  __shared__ unsigned short As[128 * 32];
  __shared__ unsigned short Bs[128 * 32];
  const int t = threadIdx.x;
  const int w = t >> 6, lane = t & 63, quad = lane >> 4, l16 = lane & 15;
  const int wm = (w >> 1) << 6, wn = (w & 1) << 6;
  const int mBase = blockIdx.x * 128, nBase = blockIdx.y * 128;

  f32x4 acc[4][4];
#pragma unroll
  for (int i = 0; i < 4; i++)
#pragma unroll
    for (int j = 0; j < 4; j++) acc[i][j] = (f32x4){0.f, 0.f, 0.f, 0.f};

  const int r0 = t >> 2;             // 0..63
  const int kk0 = (t & 3) * 8;       // 0,8,16,24

  for (int k0 = 0; k0 < K; k0 += 32) {
    gl_lds16(A + (size_t)(mBase + r0) * K + k0 + kk0, As + t * 8);
    gl_lds16(A + (size_t)(mBase + 64 + r0) * K + k0 + kk0, As + (t + 256) * 8);
    gl_lds16(B + (size_t)(nBase + r0) * K + k0 + kk0, Bs + t * 8);
    gl_lds16(B + (size_t)(nBase + 64 + r0) * K + k0 + kk0, Bs + (t + 256) * 8);
    __syncthreads();
    bf16x8 af[4], bfr[4];
#pragma unroll
    for (int i = 0; i < 4; i++)
      af[i] = *(const bf16x8*)(As + (wm + i * 16 + l16) * 32 + quad * 8);
#pragma unroll
    for (int i = 0; i < 4; i++)
      bfr[i] = *(const bf16x8*)(Bs + (wn + i * 16 + l16) * 32 + quad * 8);
#pragma unroll
    for (int mi = 0; mi < 4; mi++)
#pragma unroll
      for (int ni = 0; ni < 4; ni++)
        acc[mi][ni] = __builtin_amdgcn_mfma_f32_16x16x32_bf16(
            af[mi], bfr[ni], acc[mi][ni], 0, 0, 0);
    __syncthreads();
  }

#pragma unroll
  for (int mi = 0; mi < 4; mi++) {
#pragma unroll
    for (int r = 0; r < 4; r++) {
      const int row = mBase + wm + mi * 16 + quad * 4 + r;
#pragma unroll
      for (int ni = 0; ni < 4; ni++) {
        const int col = nBase + wn + ni * 16 + l16;
        const float v = acc[mi][ni][r];
        if (Cf) Cf[(size_t)row * N + col] = v + (bias ? bias[col] : 0.f);
        else Cbf[(size_t)row * N + col] = f2bf(v);
      }
    }
  }
}

// --------------------------- adain stats ------------------------------------
// QKV [4096, 3840] bf16; stats layout: [(which*2+{mean,std})*4 + b]*1280 + c
__global__ __launch_bounds__(BDIM) void k_stats(
    const unsigned short* __restrict__ QKV, float* __restrict__ stats) {
  const int cg = blockIdx.x, which = blockIdx.y, b = blockIdx.z;
  const int c = cg * 256 + threadIdx.x;
  const size_t base = (size_t)(b * 1024) * 3840 + which * 1280 + c;
  float s = 0.f, s2 = 0.f;
  for (int i = 0; i < 1024; ++i) {
    const float x = bf2f(QKV[base + (size_t)i * 3840]);
    s += x;
    s2 = fmaf(x, x, s2);
  }
  const float mean = s * (1.0f / 1024.0f);
  const float var = (s2 - 1024.0f * mean * mean) * (1.0f / 1023.0f);
  stats[((which * 2 + 0) * 4 + b) * 1280 + c] = mean;
  stats[((which * 2 + 1) * 4 + b) * 1280 + c] = sqrtf(var + 1e-5f);
}

// --------------------------- adain apply ------------------------------------
__global__ __launch_bounds__(BDIM) void k_adain(
    const unsigned short* __restrict__ QKV, const float* __restrict__ stats,
    unsigned short* __restrict__ qn, unsigned short* __restrict__ kn) {
  const int which = blockIdx.z, b = blockIdx.y;
  const int s = blockIdx.x / 5, cg = blockIdx.x % 5;
  const int c = cg * 256 + threadIdx.x;
  const int sb = (b < 2) ? 0 : 2;  // style batch
  const float x = bf2f(QKV[((size_t)(b * 1024 + s)) * 3840 + which * 1280 + c]);
  const float mean = stats[((which * 2 + 0) * 4 + b) * 1280 + c];
  const float stdv = stats[((which * 2 + 1) * 4 + b) * 1280 + c];
  const float meanS = stats[((which * 2 + 0) * 4 + sb) * 1280 + c];
  const float stdS = stats[((which * 2 + 1) * 4 + sb) * 1280 + c];
  const float y = (x - mean) / stdv * stdS + meanS;
  unsigned short* dst = (which == 0) ? qn : kn;
  dst[((size_t)(b * 1024 + s)) * 1280 + c] = f2bf(y);
}

// --------------------------- V transpose ------------------------------------
// QKV v-part [b, s, c] -> vt [b, c, s]   (so PV B-operand is contiguous in s)
__global__ __launch_bounds__(BDIM) void k_transpose_v(
    const unsigned short* __restrict__ QKV, unsigned short* __restrict__ vt) {
  __shared__ unsigned short tile[64][65];
  const int s0 = blockIdx.x * 64, c0 = blockIdx.y * 64, b = blockIdx.z;
  const int t = threadIdx.x;
  const int r = t >> 2, seg = (t & 3) * 16;
  const size_t goff = ((size_t)(b * 1024 + s0 + r)) * 3840 + 2560 + c0 + seg;
  const u16x8 va = *(const u16x8*)(QKV + goff);
  const u16x8 vb = *(const u16x8*)(QKV + goff + 8);
#pragma unroll
  for (int j = 0; j < 8; j++) {
    tile[r][seg + j] = va[j];
    tile[r][seg + 8 + j] = vb[j];
  }
  __syncthreads();
  u16x8 o0, o1;
#pragma unroll
  for (int j = 0; j < 8; j++) {
    o0[j] = tile[seg + j][r];
    o1[j] = tile[seg + 8 + j][r];
  }
  const size_t ooff = ((size_t)(b * 1280 + c0 + r)) * 1024 + s0 + seg;
  *(u16x8*)(vt + ooff) = o0;
  *(u16x8*)(vt + ooff + 8) = o1;
}

// --------------------------- flash attention (no-max, LDS-staged) -----------
// grid (qtile=16, h=20, b=4), 256 thr = 4 waves; wave handles 16 query rows.
// Keys/values: 0..1023 from batch b, 1024..2047 from style batch (+log2 bias).
// K/V tiles double-buffered in LDS via global_load_lds; softmax uses raw
// exp accumulation (shift-invariant; logits bounded well below fp32 exp max).
__global__ __launch_bounds__(BDIM, 4) void k_attn(
    const unsigned short* __restrict__ qn, const unsigned short* __restrict__ kn,
    const unsigned short* __restrict__ vt, unsigned short* __restrict__ out) {
  const int S = 1024, C = 1280;
  const int qt = blockIdx.x, h = blockIdx.y, b = blockIdx.z;
  const int t = threadIdx.x, w = t >> 6, lane = t & 63;
  const int quad = lane >> 4, l16 = lane & 15;
  const int bstyle = (b < 2) ? 0 : 2;
  const int qrow = qt * 64 + w * 16;

  // [buf][ {K dims0-31, K dims32-63, V keys0-31, V keys32-63} ][64*32]
  __shared__ unsigned short KV[2][4][64 * 32];
  __shared__ unsigned short Plds[4][2][16 * 32];  // [wave][key-half][q*32+key]

  const size_t qoff = ((size_t)(b * S + qrow + l16)) * C + h * 64 + quad * 8;
  const bf16x8 aq0 = *(const bf16x8*)(qn + qoff);
  const bf16x8 aq1 = *(const bf16x8*)(qn + qoff + 32);

  f32x4 o[4];
  float lsum[4] = {0.f, 0.f, 0.f, 0.f};
#pragma unroll
  for (int i = 0; i < 4; i++) o[i] = (f32x4){0.f, 0.f, 0.f, 0.f};

  const int krow = t >> 2;           // 0..63
  const int kseg = (t & 3) * 8;      // 0,8,16,24

  auto stage = [&](int buf, int kt) {
    const int kb = kt * 64;
    const int bs = (kb < S) ? b : bstyle;
    const int sk = kb & (S - 1);
    // K tile: KV[buf][0] = K[key][dims 0-31], KV[buf][1] = K[key][dims 32-63]
    const unsigned short* kg =
        kn + (size_t)(bs * S + sk + krow) * C + h * 64 + kseg;
    gl_lds16(kg, KV[buf][0] + t * 8);
    gl_lds16(kg + 32, KV[buf][1] + t * 8);
    // V tile: KV[buf][2] = V^T[dim][keys 0-31], KV[buf][3] = keys 32-63
    const unsigned short* vg =
        vt + (size_t)(bs * C + h * 64 + krow) * S + sk + kseg;
    gl_lds16(vg, KV[buf][2] + t * 8);
    gl_lds16(vg + 32, KV[buf][3] + t * 8);
  };

  stage(0, 0);

  for (int kt = 0; kt < 32; ++kt) {
    const int buf = kt & 1;
    __syncthreads();  // staging(buf) complete; prior reads of buf^1 done
    if (kt + 1 < 32) stage(buf ^ 1, kt + 1);

    const float bias = (kt >= 16) ? 0.6931471805599453f : 0.0f;

    // QK^T: 64 keys, contraction over 64 dims (2 MFMAs per 16-key group)
    f32x4 sacc[4];
#pragma unroll
    for (int nt = 0; nt < 4; ++nt) {
      const bf16x8 bk0 =
          *(const bf16x8*)(KV[buf][0] + (nt * 16 + l16) * 32 + quad * 8);
      const bf16x8 bk1 =
          *(const bf16x8*)(KV[buf][1] + (nt * 16 + l16) * 32 + quad * 8);
      f32x4 z = (f32x4){0.f, 0.f, 0.f, 0.f};
      z = __builtin_amdgcn_mfma_f32_16x16x32_bf16(aq0, bk0, z, 0, 0, 0);
      z = __builtin_amdgcn_mfma_f32_16x16x32_bf16(aq1, bk1, z, 0, 0, 0);
      sacc[nt] = z;
    }

    // p = exp(s*0.125 + bias); accumulate denominator; write P to LDS
#pragma unroll
    for (int nt = 0; nt < 4; ++nt) {
#pragma unroll
      for (int r = 0; r < 4; ++r) {
        const float e = __expf(fmaf(sacc[nt][r], 0.125f, bias));
        lsum[r] += e;
        Plds[w][nt >> 1][(quad * 4 + r) * 32 + (nt & 1) * 16 + l16] = f2bf(e);
      }
    }

    // P (A-layout) x V^T: contraction over 64 keys
    const bf16x8 pa0 = *(const bf16x8*)(Plds[w][0] + l16 * 32 + quad * 8);
    const bf16x8 pa1 = *(const bf16x8*)(Plds[w][1] + l16 * 32 + quad * 8);
#pragma unroll
    for (int dt = 0; dt < 4; ++dt) {
      const bf16x8 vb0 =
          *(const bf16x8*)(KV[buf][2] + (dt * 16 + l16) * 32 + quad * 8);
      const bf16x8 vb1 =
          *(const bf16x8*)(KV[buf][3] + (dt * 16 + l16) * 32 + quad * 8);
      o[dt] = __builtin_amdgcn_mfma_f32_16x16x32_bf16(pa0, vb0, o[dt], 0, 0, 0);
      o[dt] = __builtin_amdgcn_mfma_f32_16x16x32_bf16(pa1, vb1, o[dt], 0, 0, 0);
    }
  }

  // reduce denominator across the 16 lanes sharing each quad's rows
#pragma unroll
  for (int r = 0; r < 4; ++r) {
#pragma unroll
    for (int msk = 1; msk < 16; msk <<= 1)
      lsum[r] += __shfl_xor(lsum[r], msk, 64);
  }

#pragma unroll
  for (int dt = 0; dt < 4; ++dt)
#pragma unroll
    for (int r = 0; r < 4; ++r) {
      const int row = qrow + quad * 4 + r;
      out[((size_t)(b * S + row)) * C + h * 64 + dt * 16 + l16] =
          f2bf(o[dt][r] / lsum[r]);
    }
}

// ---------------------------------------------------------------------------
extern "C" void kernel_launch(void* const* d_in, const int* in_sizes, int n_in,
                              void* d_out, int out_size, void* d_ws,
                              size_t ws_size, hipStream_t stream) {
  const float* X = (const float*)d_in[0];
  const float* Wq = (const float*)d_in[1];
  const float* Wk = (const float*)d_in[2];
  const float* Wv = (const float*)d_in[3];
  const float* Wo = (const float*)d_in[4];
  const float* bo = (const float*)d_in[5];
  float* out = (float*)d_out;

  char* ws = (char*)d_ws;
  size_t off = 0;
  auto alloc = [&](size_t bytes) {
    char* p = ws + off;
    off += (bytes + 255) & ~(size_t)255;
    return p;
  };
  unsigned short* Xbf = (unsigned short*)alloc(4096ull * 1280 * 2);
  unsigned short* Wcat = (unsigned short*)alloc(3840ull * 1280 * 2);
  unsigned short* Wobf = (unsigned short*)alloc(1280ull * 1280 * 2);
  unsigned short* QKV = (unsigned short*)alloc(4096ull * 3840 * 2);
  float* stats = (float*)alloc(2ull * 2 * 4 * 1280 * 4);
  unsigned short* qnb = (unsigned short*)alloc(4096ull * 1280 * 2);
  unsigned short* knb = (unsigned short*)alloc(4096ull * 1280 * 2);
  unsigned short* vtb = (unsigned short*)alloc(4096ull * 1280 * 2);
  unsigned short* attn = (unsigned short*)alloc(4096ull * 1280 * 2);

  k_f32_to_bf16<<<5120, BDIM, 0, stream>>>(X, Xbf, 4096 * 1280 / 4);
  k_f32_to_bf16<<<1600, BDIM, 0, stream>>>(Wq, Wcat, 1280 * 1280 / 4);
  k_f32_to_bf16<<<1600, BDIM, 0, stream>>>(Wk, Wcat + 1280 * 1280, 1280 * 1280 / 4);
  k_f32_to_bf16<<<1600, BDIM, 0, stream>>>(Wv, Wcat + 2 * 1280 * 1280, 1280 * 1280 / 4);
  k_f32_to_bf16<<<1600, BDIM, 0, stream>>>(Wo, Wobf, 1280 * 1280 / 4);

  k_gemm_bf16<<<dim3(32, 30), BDIM, 0, stream>>>(Xbf, Wcat, QKV, nullptr,
                                                 nullptr, 4096, 3840, 1280);
  k_stats<<<dim3(5, 2, 4), BDIM, 0, stream>>>(QKV, stats);
  k_adain<<<dim3(5120, 4, 2), BDIM, 0, stream>>>(QKV, stats, qnb, knb);
  k_transpose_v<<<dim3(16, 20, 4), BDIM, 0, stream>>>(QKV, vtb);
  k_attn<<<dim3(16, 20, 4), BDIM, 0, stream>>>(qnb, knb, vtb, attn);
  k_gemm_bf16<<<dim3(32, 10), BDIM, 0, stream>>>(attn, Wobf, nullptr, out, bo,
                                                 4096, 1280, 1280);
}

// Round 3
// 348.889 us; speedup vs baseline: 1.8194x; 1.0997x over previous
//
#include <hip/hip_runtime.h>
#include <math.h>

// ---------------------------------------------------------------------------
// SharedAttentionProcessor: B=4, S=1024, C=1280, H=20, hd=64
// R3: attention uses S^T trick (mfma(K,Q) -> scores with query=col) so P
// packs to b64 LDS writes (no scatter, no conflicts); 32 queries/wave
// amortizes K/V fragment reads; stats two-stage; weight converts fused.
// ---------------------------------------------------------------------------

typedef __bf16 bf16x8 __attribute__((ext_vector_type(8)));
typedef float f32x4 __attribute__((ext_vector_type(4)));
typedef unsigned short u16x8 __attribute__((ext_vector_type(8)));

#define BDIM 256

__device__ inline unsigned short f2bf(float f) {
  unsigned int u = __float_as_uint(f);
  u += 0x7fffu + ((u >> 16) & 1u);   // RNE (inputs finite)
  return (unsigned short)(u >> 16);
}
__device__ inline unsigned int pack_bf2(float lo, float hi) {
  return (unsigned int)f2bf(lo) | ((unsigned int)f2bf(hi) << 16);
}
__device__ inline float bf2f(unsigned short h) {
  return __uint_as_float(((unsigned int)h) << 16);
}

__device__ inline void gl_lds16(const unsigned short* g, unsigned short* l) {
  __builtin_amdgcn_global_load_lds(
      (const __attribute__((address_space(1))) unsigned int*)g,
      (__attribute__((address_space(3))) unsigned int*)l, 16, 0, 0);
}

// --------------------------- fp32 -> bf16 convert ---------------------------
__global__ __launch_bounds__(BDIM) void k_f32_to_bf16(
    const float* __restrict__ src, unsigned short* __restrict__ dst, int n4) {
  int i = blockIdx.x * BDIM + threadIdx.x;
  if (i >= n4) return;
  const float4 v = ((const float4*)src)[i];
  ushort4 o;
  o.x = f2bf(v.x); o.y = f2bf(v.y); o.z = f2bf(v.z); o.w = f2bf(v.w);
  ((ushort4*)dst)[i] = o;
}

// fused convert of Wq,Wk,Wv -> Wcat and Wo -> Wobf (each 1280x1280)
__global__ __launch_bounds__(BDIM) void k_w_convert(
    const float* __restrict__ Wq, const float* __restrict__ Wk,
    const float* __restrict__ Wv, const float* __restrict__ Wo,
    unsigned short* __restrict__ Wcat, unsigned short* __restrict__ Wobf) {
  const int which = blockIdx.y;
  const float* src = (which == 0) ? Wq : (which == 1) ? Wk : (which == 2) ? Wv : Wo;
  unsigned short* dst =
      (which < 3) ? Wcat + (size_t)which * 1280 * 1280 : Wobf;
  const int i = blockIdx.x * BDIM + threadIdx.x;  // n4 = 409600
  const float4 v = ((const float4*)src)[i];
  ushort4 o;
  o.x = f2bf(v.x); o.y = f2bf(v.y); o.z = f2bf(v.z); o.w = f2bf(v.w);
  ((ushort4*)dst)[i] = o;
}

// --------------------------- bf16 GEMM (m93/m97 style) ----------------------
__global__ __launch_bounds__(BDIM) void k_gemm_bf16(
    const unsigned short* __restrict__ A, const unsigned short* __restrict__ B,
    unsigned short* __restrict__ Cbf, float* __restrict__ Cf,
    const float* __restrict__ bias, int M, int N, int K) {
  __shared__ unsigned short As[128 * 32];
  __shared__ unsigned short Bs[128 * 32];
  const int t = threadIdx.x;
  const int w = t >> 6, lane = t & 63, quad = lane >> 4, l16 = lane & 15;
  const int wm = (w >> 1) << 6, wn = (w & 1) << 6;
  const int mBase = blockIdx.x * 128, nBase = blockIdx.y * 128;

  f32x4 acc[4][4];
#pragma unroll
  for (int i = 0; i < 4; i++)
#pragma unroll
    for (int j = 0; j < 4; j++) acc[i][j] = (f32x4){0.f, 0.f, 0.f, 0.f};

  const int r0 = t >> 2;
  const int kk0 = (t & 3) * 8;

  for (int k0 = 0; k0 < K; k0 += 32) {
    gl_lds16(A + (size_t)(mBase + r0) * K + k0 + kk0, As + t * 8);
    gl_lds16(A + (size_t)(mBase + 64 + r0) * K + k0 + kk0, As + (t + 256) * 8);
    gl_lds16(B + (size_t)(nBase + r0) * K + k0 + kk0, Bs + t * 8);
    gl_lds16(B + (size_t)(nBase + 64 + r0) * K + k0 + kk0, Bs + (t + 256) * 8);
    __syncthreads();
    bf16x8 af[4], bfr[4];
#pragma unroll
    for (int i = 0; i < 4; i++)
      af[i] = *(const bf16x8*)(As + (wm + i * 16 + l16) * 32 + quad * 8);
#pragma unroll
    for (int i = 0; i < 4; i++)
      bfr[i] = *(const bf16x8*)(Bs + (wn + i * 16 + l16) * 32 + quad * 8);
#pragma unroll
    for (int mi = 0; mi < 4; mi++)
#pragma unroll
      for (int ni = 0; ni < 4; ni++)
        acc[mi][ni] = __builtin_amdgcn_mfma_f32_16x16x32_bf16(
            af[mi], bfr[ni], acc[mi][ni], 0, 0, 0);
    __syncthreads();
  }

#pragma unroll
  for (int mi = 0; mi < 4; mi++) {
#pragma unroll
    for (int r = 0; r < 4; r++) {
      const int row = mBase + wm + mi * 16 + quad * 4 + r;
#pragma unroll
      for (int ni = 0; ni < 4; ni++) {
        const int col = nBase + wn + ni * 16 + l16;
        const float v = acc[mi][ni][r];
        if (Cf) Cf[(size_t)row * N + col] = v + (bias ? bias[col] : 0.f);
        else Cbf[(size_t)row * N + col] = f2bf(v);
      }
    }
  }
}

// --------------------------- adain stats (two-stage) ------------------------
// stage 1: partial sums over 64-row chunks. grid (5, 16, 8); z = which*4+b
__global__ __launch_bounds__(BDIM) void k_stats1(
    const unsigned short* __restrict__ QKV, float* __restrict__ psum,
    float* __restrict__ psq) {
  const int z = blockIdx.z, which = z >> 2, b = z & 3;
  const int c = blockIdx.x * 256 + threadIdx.x;
  const size_t base =
      (size_t)(b * 1024 + blockIdx.y * 64) * 3840 + which * 1280 + c;
  float s = 0.f, s2 = 0.f;
#pragma unroll 4
  for (int i = 0; i < 64; ++i) {
    const float x = bf2f(QKV[base + (size_t)i * 3840]);
    s += x;
    s2 = fmaf(x, x, s2);
  }
  psum[((size_t)z * 16 + blockIdx.y) * 1280 + c] = s;
  psq[((size_t)z * 16 + blockIdx.y) * 1280 + c] = s2;
}

// stage 2: reduce 16 partials -> mean/std. grid (5, 8)
__global__ __launch_bounds__(BDIM) void k_stats2(
    const float* __restrict__ psum, const float* __restrict__ psq,
    float* __restrict__ stats) {
  const int z = blockIdx.y, which = z >> 2, b = z & 3;
  const int c = blockIdx.x * 256 + threadIdx.x;
  float s = 0.f, s2 = 0.f;
#pragma unroll
  for (int j = 0; j < 16; ++j) {
    s += psum[((size_t)z * 16 + j) * 1280 + c];
    s2 += psq[((size_t)z * 16 + j) * 1280 + c];
  }
  const float mean = s * (1.0f / 1024.0f);
  const float var = (s2 - 1024.0f * mean * mean) * (1.0f / 1023.0f);
  stats[((which * 2 + 0) * 4 + b) * 1280 + c] = mean;
  stats[((which * 2 + 1) * 4 + b) * 1280 + c] = sqrtf(var + 1e-5f);
}

// --------------------------- adain apply ------------------------------------
__global__ __launch_bounds__(BDIM) void k_adain(
    const unsigned short* __restrict__ QKV, const float* __restrict__ stats,
    unsigned short* __restrict__ qn, unsigned short* __restrict__ kn) {
  const int which = blockIdx.z, b = blockIdx.y;
  const int s = blockIdx.x / 5, cg = blockIdx.x % 5;
  const int c = cg * 256 + threadIdx.x;
  const int sb = (b < 2) ? 0 : 2;
  const float x = bf2f(QKV[((size_t)(b * 1024 + s)) * 3840 + which * 1280 + c]);
  const float mean = stats[((which * 2 + 0) * 4 + b) * 1280 + c];
  const float stdv = stats[((which * 2 + 1) * 4 + b) * 1280 + c];
  const float meanS = stats[((which * 2 + 0) * 4 + sb) * 1280 + c];
  const float stdS = stats[((which * 2 + 1) * 4 + sb) * 1280 + c];
  const float y = (x - mean) / stdv * stdS + meanS;
  unsigned short* dst = (which == 0) ? qn : kn;
  dst[((size_t)(b * 1024 + s)) * 1280 + c] = f2bf(y);
}

// --------------------------- V transpose ------------------------------------
__global__ __launch_bounds__(BDIM) void k_transpose_v(
    const unsigned short* __restrict__ QKV, unsigned short* __restrict__ vt) {
  __shared__ unsigned short tile[64][65];
  const int s0 = blockIdx.x * 64, c0 = blockIdx.y * 64, b = blockIdx.z;
  const int t = threadIdx.x;
  const int r = t >> 2, seg = (t & 3) * 16;
  const size_t goff = ((size_t)(b * 1024 + s0 + r)) * 3840 + 2560 + c0 + seg;
  const u16x8 va = *(const u16x8*)(QKV + goff);
  const u16x8 vb = *(const u16x8*)(QKV + goff + 8);
#pragma unroll
  for (int j = 0; j < 8; j++) {
    tile[r][seg + j] = va[j];
    tile[r][seg + 8 + j] = vb[j];
  }
  __syncthreads();
  u16x8 o0, o1;
#pragma unroll
  for (int j = 0; j < 8; j++) {
    o0[j] = tile[seg + j][r];
    o1[j] = tile[seg + 8 + j][r];
  }
  const size_t ooff = ((size_t)(b * 1280 + c0 + r)) * 1024 + s0 + seg;
  *(u16x8*)(vt + ooff) = o0;
  *(u16x8*)(vt + ooff + 8) = o1;
}

// --------------------------- flash attention --------------------------------
// grid (8, 20, 4): 128 queries/block, 32/wave (two 16-query groups).
// S^T trick: scores = mfma(K-frag, Q-frag) -> D[m=key][n=query]; each lane's
// 16 scores belong to query l16 with keys nt*16+quad*4+r -> P packs to b64
// writes at row=query (conflict-free). exp in log2 domain (bias -> exactly 1).
__global__ __launch_bounds__(BDIM, 3) void k_attn(
    const unsigned short* __restrict__ qn, const unsigned short* __restrict__ kn,
    const unsigned short* __restrict__ vt, unsigned short* __restrict__ out) {
  const int S = 1024, C = 1280;
  const int qt = blockIdx.x, h = blockIdx.y, b = blockIdx.z;
  const int t = threadIdx.x, w = t >> 6, lane = t & 63;
  const int quad = lane >> 4, l16 = lane & 15;
  const int bstyle = (b < 2) ? 0 : 2;
  const int qrow = qt * 128 + w * 32;  // wave's 32 queries

  __shared__ unsigned short KV[2][4][64 * 32];
  __shared__ unsigned short Plds[4][32][72];  // [wave][query row][64 keys + pad]

  bf16x8 aq[2][2];
#pragma unroll
  for (int g = 0; g < 2; ++g) {
    const size_t qoff =
        ((size_t)(b * S + qrow + g * 16 + l16)) * C + h * 64 + quad * 8;
    aq[g][0] = *(const bf16x8*)(qn + qoff);
    aq[g][1] = *(const bf16x8*)(qn + qoff + 32);
  }

  f32x4 o[2][4];
  float lsum[2] = {0.f, 0.f};
#pragma unroll
  for (int g = 0; g < 2; ++g)
#pragma unroll
    for (int i = 0; i < 4; i++) o[g][i] = (f32x4){0.f, 0.f, 0.f, 0.f};

  const int krow = t >> 2;
  const int kseg = (t & 3) * 8;

  auto stage = [&](int buf, int kt) {
    const int kb = kt * 64;
    const int bs = (kb < S) ? b : bstyle;
    const int sk = kb & (S - 1);
    const unsigned short* kg =
        kn + (size_t)(bs * S + sk + krow) * C + h * 64 + kseg;
    gl_lds16(kg, KV[buf][0] + t * 8);
    gl_lds16(kg + 32, KV[buf][1] + t * 8);
    const unsigned short* vg =
        vt + (size_t)(bs * C + h * 64 + krow) * S + sk + kseg;
    gl_lds16(vg, KV[buf][2] + t * 8);
    gl_lds16(vg + 32, KV[buf][3] + t * 8);
  };

  stage(0, 0);

  const float SCALE2 = 0.125f * 1.44269504088896341f;  // logit scale, log2 dom

  for (int kt = 0; kt < 32; ++kt) {
    const int buf = kt & 1;
    __syncthreads();
    if (kt + 1 < 32) stage(buf ^ 1, kt + 1);

    const float bias2 = (kt >= 16) ? 1.0f : 0.0f;  // log2(exp(log 2)) = 1

    // S^T: D[m=key (nt*16+quad*4+r)][n=query l16]
    f32x4 z[2][4];
#pragma unroll
    for (int nt = 0; nt < 4; ++nt) {
      const bf16x8 bk0 =
          *(const bf16x8*)(KV[buf][0] + (nt * 16 + l16) * 32 + quad * 8);
      const bf16x8 bk1 =
          *(const bf16x8*)(KV[buf][1] + (nt * 16 + l16) * 32 + quad * 8);
#pragma unroll
      for (int g = 0; g < 2; ++g) {
        f32x4 zz = (f32x4){0.f, 0.f, 0.f, 0.f};
        zz = __builtin_amdgcn_mfma_f32_16x16x32_bf16(bk0, aq[g][0], zz, 0, 0, 0);
        zz = __builtin_amdgcn_mfma_f32_16x16x32_bf16(bk1, aq[g][1], zz, 0, 0, 0);
        z[g][nt] = zz;
      }
    }

    // exp2, denominator accumulate, pack 4 consecutive keys -> one b64 write
#pragma unroll
    for (int g = 0; g < 2; ++g) {
#pragma unroll
      for (int nt = 0; nt < 4; ++nt) {
        const float e0 = exp2f(fmaf(z[g][nt][0], SCALE2, bias2));
        const float e1 = exp2f(fmaf(z[g][nt][1], SCALE2, bias2));
        const float e2 = exp2f(fmaf(z[g][nt][2], SCALE2, bias2));
        const float e3 = exp2f(fmaf(z[g][nt][3], SCALE2, bias2));
        lsum[g] += (e0 + e1) + (e2 + e3);
        uint2 pk;
        pk.x = pack_bf2(e0, e1);
        pk.y = pack_bf2(e2, e3);
        *(uint2*)(&Plds[w][g * 16 + l16][nt * 16 + quad * 4]) = pk;
      }
    }

    // P (A-layout: row=query l16, keys quad*8..) x V^T
#pragma unroll
    for (int dt = 0; dt < 4; ++dt) {
      const bf16x8 vb0 =
          *(const bf16x8*)(KV[buf][2] + (dt * 16 + l16) * 32 + quad * 8);
      const bf16x8 vb1 =
          *(const bf16x8*)(KV[buf][3] + (dt * 16 + l16) * 32 + quad * 8);
#pragma unroll
      for (int g = 0; g < 2; ++g) {
        const bf16x8 pa0 = *(const bf16x8*)(&Plds[w][g * 16 + l16][quad * 8]);
        const bf16x8 pa1 =
            *(const bf16x8*)(&Plds[w][g * 16 + l16][32 + quad * 8]);
        o[g][dt] =
            __builtin_amdgcn_mfma_f32_16x16x32_bf16(pa0, vb0, o[g][dt], 0, 0, 0);
        o[g][dt] =
            __builtin_amdgcn_mfma_f32_16x16x32_bf16(pa1, vb1, o[g][dt], 0, 0, 0);
      }
    }
  }

  // total denominator per query: reduce across the 4 quads (lanes +-16/32/48)
#pragma unroll
  for (int g = 0; g < 2; ++g) {
    lsum[g] += __shfl_xor(lsum[g], 16, 64);
    lsum[g] += __shfl_xor(lsum[g], 32, 64);
  }

#pragma unroll
  for (int g = 0; g < 2; ++g) {
    float rinv[4];
#pragma unroll
    for (int r = 0; r < 4; ++r)
      rinv[r] = 1.0f / __shfl(lsum[g], quad * 4 + r, 64);
#pragma unroll
    for (int dt = 0; dt < 4; ++dt)
#pragma unroll
      for (int r = 0; r < 4; ++r) {
        const int row = qrow + g * 16 + quad * 4 + r;
        out[((size_t)(b * S + row)) * C + h * 64 + dt * 16 + l16] =
            f2bf(o[g][dt][r] * rinv[r]);
      }
  }
}

// ---------------------------------------------------------------------------
extern "C" void kernel_launch(void* const* d_in, const int* in_sizes, int n_in,
                              void* d_out, int out_size, void* d_ws,
                              size_t ws_size, hipStream_t stream) {
  const float* X = (const float*)d_in[0];
  const float* Wq = (const float*)d_in[1];
  const float* Wk = (const float*)d_in[2];
  const float* Wv = (const float*)d_in[3];
  const float* Wo = (const float*)d_in[4];
  const float* bo = (const float*)d_in[5];
  float* out = (float*)d_out;

  char* ws = (char*)d_ws;
  size_t off = 0;
  auto alloc = [&](size_t bytes) {
    char* p = ws + off;
    off += (bytes + 255) & ~(size_t)255;
    return p;
  };
  unsigned short* Xbf = (unsigned short*)alloc(4096ull * 1280 * 2);
  unsigned short* Wcat = (unsigned short*)alloc(3840ull * 1280 * 2);
  unsigned short* Wobf = (unsigned short*)alloc(1280ull * 1280 * 2);
  unsigned short* QKV = (unsigned short*)alloc(4096ull * 3840 * 2);
  float* stats = (float*)alloc(2ull * 2 * 4 * 1280 * 4);
  float* psum = (float*)alloc(8ull * 16 * 1280 * 4);
  float* psq = (float*)alloc(8ull * 16 * 1280 * 4);
  unsigned short* qnb = (unsigned short*)alloc(4096ull * 1280 * 2);
  unsigned short* knb = (unsigned short*)alloc(4096ull * 1280 * 2);
  unsigned short* vtb = (unsigned short*)alloc(4096ull * 1280 * 2);
  unsigned short* attn = (unsigned short*)alloc(4096ull * 1280 * 2);

  k_f32_to_bf16<<<5120, BDIM, 0, stream>>>(X, Xbf, 4096 * 1280 / 4);
  k_w_convert<<<dim3(1600, 4), BDIM, 0, stream>>>(Wq, Wk, Wv, Wo, Wcat, Wobf);

  k_gemm_bf16<<<dim3(32, 30), BDIM, 0, stream>>>(Xbf, Wcat, QKV, nullptr,
                                                 nullptr, 4096, 3840, 1280);
  k_stats1<<<dim3(5, 16, 8), BDIM, 0, stream>>>(QKV, psum, psq);
  k_stats2<<<dim3(5, 8), BDIM, 0, stream>>>(psum, psq, stats);
  k_adain<<<dim3(5120, 4, 2), BDIM, 0, stream>>>(QKV, stats, qnb, knb);
  k_transpose_v<<<dim3(16, 20, 4), BDIM, 0, stream>>>(QKV, vtb);
  k_attn<<<dim3(8, 20, 4), BDIM, 0, stream>>>(qnb, knb, vtb, attn);
  k_gemm_bf16<<<dim3(32, 10), BDIM, 0, stream>>>(attn, Wobf, nullptr, out, bo,
                                                 4096, 1280, 1280);
}

// Round 4
// 314.986 us; speedup vs baseline: 2.0152x; 1.1076x over previous
//
#include <hip/hip_runtime.h>
#include <math.h>

// ---------------------------------------------------------------------------
// SharedAttentionProcessor: B=4, H=20, S=1024, C=1280, hd=64
// R4: attention split-K x2 (grid 1280) + even-batch dedup (style==self =>
// plain softmax over 1024 keys) + XOR-swizzled P (floor-level LDS conflicts)
// + fp32 partial combine kernel; out-GEMM re-tiled 64x128 (grid 640).
// ---------------------------------------------------------------------------

typedef __bf16 bf16x8 __attribute__((ext_vector_type(8)));
typedef float f32x4 __attribute__((ext_vector_type(4)));
typedef unsigned short u16x8 __attribute__((ext_vector_type(8)));

#define BDIM 256

__device__ inline unsigned short f2bf(float f) {
  unsigned int u = __float_as_uint(f);
  u += 0x7fffu + ((u >> 16) & 1u);   // RNE (inputs finite)
  return (unsigned short)(u >> 16);
}
__device__ inline unsigned int pack_bf2(float lo, float hi) {
  return (unsigned int)f2bf(lo) | ((unsigned int)f2bf(hi) << 16);
}
__device__ inline float bf2f(unsigned short h) {
  return __uint_as_float(((unsigned int)h) << 16);
}

__device__ inline void gl_lds16(const unsigned short* g, unsigned short* l) {
  __builtin_amdgcn_global_load_lds(
      (const __attribute__((address_space(1))) unsigned int*)g,
      (__attribute__((address_space(3))) unsigned int*)l, 16, 0, 0);
}

// --------------------------- fp32 -> bf16 convert ---------------------------
__global__ __launch_bounds__(BDIM) void k_f32_to_bf16(
    const float* __restrict__ src, unsigned short* __restrict__ dst, int n4) {
  int i = blockIdx.x * BDIM + threadIdx.x;
  if (i >= n4) return;
  const float4 v = ((const float4*)src)[i];
  ushort4 o;
  o.x = f2bf(v.x); o.y = f2bf(v.y); o.z = f2bf(v.z); o.w = f2bf(v.w);
  ((ushort4*)dst)[i] = o;
}

// fused convert of Wq,Wk,Wv -> Wcat and Wo -> Wobf (each 1280x1280)
__global__ __launch_bounds__(BDIM) void k_w_convert(
    const float* __restrict__ Wq, const float* __restrict__ Wk,
    const float* __restrict__ Wv, const float* __restrict__ Wo,
    unsigned short* __restrict__ Wcat, unsigned short* __restrict__ Wobf) {
  const int which = blockIdx.y;
  const float* src = (which == 0) ? Wq : (which == 1) ? Wk : (which == 2) ? Wv : Wo;
  unsigned short* dst =
      (which < 3) ? Wcat + (size_t)which * 1280 * 1280 : Wobf;
  const int i = blockIdx.x * BDIM + threadIdx.x;  // n4 = 409600
  const float4 v = ((const float4*)src)[i];
  ushort4 o;
  o.x = f2bf(v.x); o.y = f2bf(v.y); o.z = f2bf(v.z); o.w = f2bf(v.w);
  ((ushort4*)dst)[i] = o;
}

// --------------------------- bf16 GEMM 128x128 (QKV) ------------------------
__global__ __launch_bounds__(BDIM) void k_gemm_bf16(
    const unsigned short* __restrict__ A, const unsigned short* __restrict__ B,
    unsigned short* __restrict__ Cbf, int M, int N, int K) {
  __shared__ unsigned short As[128 * 32];
  __shared__ unsigned short Bs[128 * 32];
  const int t = threadIdx.x;
  const int w = t >> 6, lane = t & 63, quad = lane >> 4, l16 = lane & 15;
  const int wm = (w >> 1) << 6, wn = (w & 1) << 6;
  const int mBase = blockIdx.x * 128, nBase = blockIdx.y * 128;

  f32x4 acc[4][4];
#pragma unroll
  for (int i = 0; i < 4; i++)
#pragma unroll
    for (int j = 0; j < 4; j++) acc[i][j] = (f32x4){0.f, 0.f, 0.f, 0.f};

  const int r0 = t >> 2;
  const int kk0 = (t & 3) * 8;

  for (int k0 = 0; k0 < K; k0 += 32) {
    gl_lds16(A + (size_t)(mBase + r0) * K + k0 + kk0, As + t * 8);
    gl_lds16(A + (size_t)(mBase + 64 + r0) * K + k0 + kk0, As + (t + 256) * 8);
    gl_lds16(B + (size_t)(nBase + r0) * K + k0 + kk0, Bs + t * 8);
    gl_lds16(B + (size_t)(nBase + 64 + r0) * K + k0 + kk0, Bs + (t + 256) * 8);
    __syncthreads();
    bf16x8 af[4], bfr[4];
#pragma unroll
    for (int i = 0; i < 4; i++)
      af[i] = *(const bf16x8*)(As + (wm + i * 16 + l16) * 32 + quad * 8);
#pragma unroll
    for (int i = 0; i < 4; i++)
      bfr[i] = *(const bf16x8*)(Bs + (wn + i * 16 + l16) * 32 + quad * 8);
#pragma unroll
    for (int mi = 0; mi < 4; mi++)
#pragma unroll
      for (int ni = 0; ni < 4; ni++)
        acc[mi][ni] = __builtin_amdgcn_mfma_f32_16x16x32_bf16(
            af[mi], bfr[ni], acc[mi][ni], 0, 0, 0);
    __syncthreads();
  }

#pragma unroll
  for (int mi = 0; mi < 4; mi++)
#pragma unroll
    for (int r = 0; r < 4; r++) {
      const int row = mBase + wm + mi * 16 + quad * 4 + r;
#pragma unroll
      for (int ni = 0; ni < 4; ni++)
        Cbf[(size_t)row * N + nBase + wn + ni * 16 + l16] = f2bf(acc[mi][ni][r]);
    }
}

// --------------------------- bf16 GEMM 64x128 (out proj) --------------------
__global__ __launch_bounds__(BDIM) void k_gemm_64x128(
    const unsigned short* __restrict__ A, const unsigned short* __restrict__ B,
    float* __restrict__ Cf, const float* __restrict__ bias, int M, int N,
    int K) {
  __shared__ unsigned short As[64 * 32];
  __shared__ unsigned short Bs[128 * 32];
  const int t = threadIdx.x;
  const int w = t >> 6, lane = t & 63, quad = lane >> 4, l16 = lane & 15;
  const int wm = (w >> 1) << 5, wn = (w & 1) << 6;
  const int mBase = blockIdx.x * 64, nBase = blockIdx.y * 128;

  f32x4 acc[2][4];
#pragma unroll
  for (int i = 0; i < 2; i++)
#pragma unroll
    for (int j = 0; j < 4; j++) acc[i][j] = (f32x4){0.f, 0.f, 0.f, 0.f};

  const int r0 = t >> 2;
  const int kk0 = (t & 3) * 8;

  for (int k0 = 0; k0 < K; k0 += 32) {
    gl_lds16(A + (size_t)(mBase + r0) * K + k0 + kk0, As + t * 8);
    gl_lds16(B + (size_t)(nBase + r0) * K + k0 + kk0, Bs + t * 8);
    gl_lds16(B + (size_t)(nBase + 64 + r0) * K + k0 + kk0, Bs + (t + 256) * 8);
    __syncthreads();
    bf16x8 af[2], bfr[4];
#pragma unroll
    for (int i = 0; i < 2; i++)
      af[i] = *(const bf16x8*)(As + (wm + i * 16 + l16) * 32 + quad * 8);
#pragma unroll
    for (int i = 0; i < 4; i++)
      bfr[i] = *(const bf16x8*)(Bs + (wn + i * 16 + l16) * 32 + quad * 8);
#pragma unroll
    for (int mi = 0; mi < 2; mi++)
#pragma unroll
      for (int ni = 0; ni < 4; ni++)
        acc[mi][ni] = __builtin_amdgcn_mfma_f32_16x16x32_bf16(
            af[mi], bfr[ni], acc[mi][ni], 0, 0, 0);
    __syncthreads();
  }

#pragma unroll
  for (int mi = 0; mi < 2; mi++)
#pragma unroll
    for (int r = 0; r < 4; r++) {
      const int row = mBase + wm + mi * 16 + quad * 4 + r;
#pragma unroll
      for (int ni = 0; ni < 4; ni++) {
        const int col = nBase + wn + ni * 16 + l16;
        Cf[(size_t)row * N + col] = acc[mi][ni][r] + bias[col];
      }
    }
}

// --------------------------- adain stats (two-stage) ------------------------
__global__ __launch_bounds__(BDIM) void k_stats1(
    const unsigned short* __restrict__ QKV, float* __restrict__ psum,
    float* __restrict__ psq) {
  const int z = blockIdx.z, which = z >> 2, b = z & 3;
  const int c = blockIdx.x * 256 + threadIdx.x;
  const size_t base =
      (size_t)(b * 1024 + blockIdx.y * 64) * 3840 + which * 1280 + c;
  float s = 0.f, s2 = 0.f;
#pragma unroll 4
  for (int i = 0; i < 64; ++i) {
    const float x = bf2f(QKV[base + (size_t)i * 3840]);
    s += x;
    s2 = fmaf(x, x, s2);
  }
  psum[((size_t)z * 16 + blockIdx.y) * 1280 + c] = s;
  psq[((size_t)z * 16 + blockIdx.y) * 1280 + c] = s2;
}

__global__ __launch_bounds__(BDIM) void k_stats2(
    const float* __restrict__ psum, const float* __restrict__ psq,
    float* __restrict__ stats) {
  const int z = blockIdx.y, which = z >> 2, b = z & 3;
  const int c = blockIdx.x * 256 + threadIdx.x;
  float s = 0.f, s2 = 0.f;
#pragma unroll
  for (int j = 0; j < 16; ++j) {
    s += psum[((size_t)z * 16 + j) * 1280 + c];
    s2 += psq[((size_t)z * 16 + j) * 1280 + c];
  }
  const float mean = s * (1.0f / 1024.0f);
  const float var = (s2 - 1024.0f * mean * mean) * (1.0f / 1023.0f);
  stats[((which * 2 + 0) * 4 + b) * 1280 + c] = mean;
  stats[((which * 2 + 1) * 4 + b) * 1280 + c] = sqrtf(var + 1e-5f);
}

// --------------------------- adain apply ------------------------------------
__global__ __launch_bounds__(BDIM) void k_adain(
    const unsigned short* __restrict__ QKV, const float* __restrict__ stats,
    unsigned short* __restrict__ qn, unsigned short* __restrict__ kn) {
  const int which = blockIdx.z, b = blockIdx.y;
  const int s = blockIdx.x / 5, cg = blockIdx.x % 5;
  const int c = cg * 256 + threadIdx.x;
  const int sb = (b < 2) ? 0 : 2;
  const float x = bf2f(QKV[((size_t)(b * 1024 + s)) * 3840 + which * 1280 + c]);
  const float mean = stats[((which * 2 + 0) * 4 + b) * 1280 + c];
  const float stdv = stats[((which * 2 + 1) * 4 + b) * 1280 + c];
  const float meanS = stats[((which * 2 + 0) * 4 + sb) * 1280 + c];
  const float stdS = stats[((which * 2 + 1) * 4 + sb) * 1280 + c];
  const float y = (x - mean) / stdv * stdS + meanS;
  unsigned short* dst = (which == 0) ? qn : kn;
  dst[((size_t)(b * 1024 + s)) * 1280 + c] = f2bf(y);
}

// --------------------------- V transpose ------------------------------------
__global__ __launch_bounds__(BDIM) void k_transpose_v(
    const unsigned short* __restrict__ QKV, unsigned short* __restrict__ vt) {
  __shared__ unsigned short tile[64][65];
  const int s0 = blockIdx.x * 64, c0 = blockIdx.y * 64, b = blockIdx.z;
  const int t = threadIdx.x;
  const int r = t >> 2, seg = (t & 3) * 16;
  const size_t goff = ((size_t)(b * 1024 + s0 + r)) * 3840 + 2560 + c0 + seg;
  const u16x8 va = *(const u16x8*)(QKV + goff);
  const u16x8 vb = *(const u16x8*)(QKV + goff + 8);
#pragma unroll
  for (int j = 0; j < 8; j++) {
    tile[r][seg + j] = va[j];
    tile[r][seg + 8 + j] = vb[j];
  }
  __syncthreads();
  u16x8 o0, o1;
#pragma unroll
  for (int j = 0; j < 8; j++) {
    o0[j] = tile[seg + j][r];
    o1[j] = tile[seg + 8 + j][r];
  }
  const size_t ooff = ((size_t)(b * 1280 + c0 + r)) * 1024 + s0 + seg;
  *(u16x8*)(vt + ooff) = o0;
  *(u16x8*)(vt + ooff + 8) = o1;
}

// --------------------------- flash attention (split-K x2) -------------------
// grid (8*2, 20, 4): x = qt*2+kh. 128 queries/block, 32/wave.
// b even: style==self => plain softmax over 1024 own keys (factor 3 cancels);
//         kh halves split 16 own key-tiles 8/8.
// b odd:  kh=0 -> own keys kt 0..15; kh=1 -> style keys kt 16..31 (+log2).
// P buffer XOR-swizzled (granule ^ (l16&14)) -> floor-level bank conflicts.
// Outputs fp32 partial O (pre-division) + per-query denominator partial.
__global__ __launch_bounds__(BDIM, 3) void k_attn(
    const unsigned short* __restrict__ qn, const unsigned short* __restrict__ kn,
    const unsigned short* __restrict__ vt, float* __restrict__ Opart,
    float* __restrict__ Lpart) {
  const int S = 1024, C = 1280;
  const int qt = blockIdx.x >> 1, kh = blockIdx.x & 1;
  const int h = blockIdx.y, b = blockIdx.z;
  const int t = threadIdx.x, w = t >> 6, lane = t & 63;
  const int quad = lane >> 4, l16 = lane & 15;
  const int bstyle = (b < 2) ? 0 : 2;
  const int qrow = qt * 128 + w * 32;

  int ktBeg, ktEnd;
  if (b & 1) { ktBeg = kh * 16; ktEnd = ktBeg + 16; }
  else       { ktBeg = kh * 8;  ktEnd = ktBeg + 8; }

  __shared__ unsigned short KV[2][4][64 * 32];
  __shared__ unsigned short Plds[4][32][64];  // XOR-swizzled, no pad

  bf16x8 aq[2][2];
#pragma unroll
  for (int g = 0; g < 2; ++g) {
    const size_t qoff =
        ((size_t)(b * S + qrow + g * 16 + l16)) * C + h * 64 + quad * 8;
    aq[g][0] = *(const bf16x8*)(qn + qoff);
    aq[g][1] = *(const bf16x8*)(qn + qoff + 32);
  }

  f32x4 o[2][4];
  float lsum[2] = {0.f, 0.f};
#pragma unroll
  for (int g = 0; g < 2; ++g)
#pragma unroll
    for (int i = 0; i < 4; i++) o[g][i] = (f32x4){0.f, 0.f, 0.f, 0.f};

  const int krow = t >> 2;
  const int kseg = (t & 3) * 8;
  const int sw = l16 & 14;  // P-granule XOR swizzle

  auto stage = [&](int buf, int kt) {
    const int bs = (kt < 16) ? b : bstyle;
    const int sk = (kt & 15) * 64;
    const unsigned short* kg =
        kn + (size_t)(bs * S + sk + krow) * C + h * 64 + kseg;
    gl_lds16(kg, KV[buf][0] + t * 8);
    gl_lds16(kg + 32, KV[buf][1] + t * 8);
    const unsigned short* vg =
        vt + (size_t)(bs * C + h * 64 + krow) * S + sk + kseg;
    gl_lds16(vg, KV[buf][2] + t * 8);
    gl_lds16(vg + 32, KV[buf][3] + t * 8);
  };

  stage(0, ktBeg);

  const float SCALE2 = 0.125f * 1.44269504088896341f;  // logit scale, log2 dom

  for (int kt = ktBeg; kt < ktEnd; ++kt) {
    const int buf = (kt - ktBeg) & 1;
    __syncthreads();
    if (kt + 1 < ktEnd) stage(buf ^ 1, kt + 1);

    const float bias2 = (kt >= 16) ? 1.0f : 0.0f;  // only reachable for b odd

    // S^T: D[m=key (nt*16+quad*4+r)][n=query l16]
    f32x4 z[2][4];
#pragma unroll
    for (int nt = 0; nt < 4; ++nt) {
      const bf16x8 bk0 =
          *(const bf16x8*)(KV[buf][0] + (nt * 16 + l16) * 32 + quad * 8);
      const bf16x8 bk1 =
          *(const bf16x8*)(KV[buf][1] + (nt * 16 + l16) * 32 + quad * 8);
#pragma unroll
      for (int g = 0; g < 2; ++g) {
        f32x4 zz = (f32x4){0.f, 0.f, 0.f, 0.f};
        zz = __builtin_amdgcn_mfma_f32_16x16x32_bf16(bk0, aq[g][0], zz, 0, 0, 0);
        zz = __builtin_amdgcn_mfma_f32_16x16x32_bf16(bk1, aq[g][1], zz, 0, 0, 0);
        z[g][nt] = zz;
      }
    }

    // exp2, denominator accumulate, pack 4 keys -> one b64 swizzled write
#pragma unroll
    for (int g = 0; g < 2; ++g) {
#pragma unroll
      for (int nt = 0; nt < 4; ++nt) {
        const float e0 = exp2f(fmaf(z[g][nt][0], SCALE2, bias2));
        const float e1 = exp2f(fmaf(z[g][nt][1], SCALE2, bias2));
        const float e2 = exp2f(fmaf(z[g][nt][2], SCALE2, bias2));
        const float e3 = exp2f(fmaf(z[g][nt][3], SCALE2, bias2));
        lsum[g] += (e0 + e1) + (e2 + e3);
        uint2 pk;
        pk.x = pack_bf2(e0, e1);
        pk.y = pack_bf2(e2, e3);
        const int phys = (nt * 4 + quad) ^ sw;
        *(uint2*)(&Plds[w][g * 16 + l16][phys * 4]) = pk;
      }
    }

    // P (A-layout via swizzled read) x V^T
#pragma unroll
    for (int dt = 0; dt < 4; ++dt) {
      const bf16x8 vb0 =
          *(const bf16x8*)(KV[buf][2] + (dt * 16 + l16) * 32 + quad * 8);
      const bf16x8 vb1 =
          *(const bf16x8*)(KV[buf][3] + (dt * 16 + l16) * 32 + quad * 8);
#pragma unroll
      for (int g = 0; g < 2; ++g) {
        const int a0 = (2 * quad) ^ sw;
        const int a1 = (2 * quad + 8) ^ sw;
        const bf16x8 pa0 = *(const bf16x8*)(&Plds[w][g * 16 + l16][a0 * 4]);
        const bf16x8 pa1 = *(const bf16x8*)(&Plds[w][g * 16 + l16][a1 * 4]);
        o[g][dt] =
            __builtin_amdgcn_mfma_f32_16x16x32_bf16(pa0, vb0, o[g][dt], 0, 0, 0);
        o[g][dt] =
            __builtin_amdgcn_mfma_f32_16x16x32_bf16(pa1, vb1, o[g][dt], 0, 0, 0);
      }
    }
  }

  // denominator: reduce across the 4 quads; all lanes then hold query l16's sum
#pragma unroll
  for (int g = 0; g < 2; ++g) {
    lsum[g] += __shfl_xor(lsum[g], 16, 64);
    lsum[g] += __shfl_xor(lsum[g], 32, 64);
    if (quad == 0)
      Lpart[(((size_t)kh * 4 + b) * 20 + h) * 1024 + qrow + g * 16 + l16] =
          lsum[g];
  }

  float* Op = Opart + (size_t)kh * 4096 * 1280;
#pragma unroll
  for (int g = 0; g < 2; ++g)
#pragma unroll
    for (int dt = 0; dt < 4; ++dt)
#pragma unroll
      for (int r = 0; r < 4; ++r) {
        const int row = qrow + g * 16 + quad * 4 + r;
        Op[((size_t)(b * S + row)) * C + h * 64 + dt * 16 + l16] = o[g][dt][r];
      }
}

// --------------------------- combine split-K partials -----------------------
__global__ __launch_bounds__(BDIM) void k_combine(
    const float* __restrict__ Opart, const float* __restrict__ Lpart,
    unsigned short* __restrict__ attnb) {
  const int idx = blockIdx.x * BDIM + threadIdx.x;  // 1,310,720 threads
  const int i = idx * 4;
  const int row = i / 1280, c = i % 1280;
  const int b = row >> 10, q = row & 1023, h = c >> 6;
  const float4 o0 = *(const float4*)(Opart + (size_t)i);
  const float4 o1 = *(const float4*)(Opart + (size_t)4096 * 1280 + i);
  const size_t li = (((size_t)b) * 20 + h) * 1024 + q;
  const float rl = 1.0f / (Lpart[li] + Lpart[4 * 20 * 1024 + li]);
  ushort4 o;
  o.x = f2bf((o0.x + o1.x) * rl);
  o.y = f2bf((o0.y + o1.y) * rl);
  o.z = f2bf((o0.z + o1.z) * rl);
  o.w = f2bf((o0.w + o1.w) * rl);
  *(ushort4*)(attnb + i) = o;
}

// ---------------------------------------------------------------------------
extern "C" void kernel_launch(void* const* d_in, const int* in_sizes, int n_in,
                              void* d_out, int out_size, void* d_ws,
                              size_t ws_size, hipStream_t stream) {
  const float* X = (const float*)d_in[0];
  const float* Wq = (const float*)d_in[1];
  const float* Wk = (const float*)d_in[2];
  const float* Wv = (const float*)d_in[3];
  const float* Wo = (const float*)d_in[4];
  const float* bo = (const float*)d_in[5];
  float* out = (float*)d_out;

  char* ws = (char*)d_ws;
  size_t off = 0;
  auto alloc = [&](size_t bytes) {
    char* p = ws + off;
    off += (bytes + 255) & ~(size_t)255;
    return p;
  };
  // Lifetimes: Wcat,Xbf,QKV dead before attn -> Opart aliases Xbf+QKV (exact);
  // Lpart aliases Wcat; psum/psq alias attnb (live disjoint).
  unsigned short* Wcat = (unsigned short*)alloc(3840ull * 1280 * 2);
  unsigned short* Xbf = (unsigned short*)alloc(4096ull * 1280 * 2);
  unsigned short* QKV = (unsigned short*)alloc(4096ull * 3840 * 2);
  unsigned short* Wobf = (unsigned short*)alloc(1280ull * 1280 * 2);
  float* stats = (float*)alloc(2ull * 2 * 4 * 1280 * 4);
  unsigned short* qnb = (unsigned short*)alloc(4096ull * 1280 * 2);
  unsigned short* knb = (unsigned short*)alloc(4096ull * 1280 * 2);
  unsigned short* vtb = (unsigned short*)alloc(4096ull * 1280 * 2);
  unsigned short* attnb = (unsigned short*)alloc(4096ull * 1280 * 2);

  float* Opart = (float*)Xbf;          // 2 x 4096 x 1280 fp32 = Xbf+QKV exactly
  float* Lpart = (float*)Wcat;         // 2 x 4 x 20 x 1024 fp32 = 640 KB
  float* psum = (float*)attnb;         // 8 x 16 x 1280 fp32 = 640 KB
  float* psq = (float*)(attnb + 4096ull * 1280 / 2);  // second 640 KB half

  k_f32_to_bf16<<<5120, BDIM, 0, stream>>>(X, Xbf, 4096 * 1280 / 4);
  k_w_convert<<<dim3(1600, 4), BDIM, 0, stream>>>(Wq, Wk, Wv, Wo, Wcat, Wobf);

  k_gemm_bf16<<<dim3(32, 30), BDIM, 0, stream>>>(Xbf, Wcat, QKV, 4096, 3840,
                                                 1280);
  k_stats1<<<dim3(5, 16, 8), BDIM, 0, stream>>>(QKV, psum, psq);
  k_stats2<<<dim3(5, 8), BDIM, 0, stream>>>(psum, psq, stats);
  k_adain<<<dim3(5120, 4, 2), BDIM, 0, stream>>>(QKV, stats, qnb, knb);
  k_transpose_v<<<dim3(16, 20, 4), BDIM, 0, stream>>>(QKV, vtb);
  k_attn<<<dim3(16, 20, 4), BDIM, 0, stream>>>(qnb, knb, vtb, Opart, Lpart);
  k_combine<<<5120, BDIM, 0, stream>>>(Opart, Lpart, attnb);
  k_gemm_64x128<<<dim3(64, 10), BDIM, 0, stream>>>(attnb, Wobf, out, bo, 4096,
                                                   1280, 1280);
}

// Round 5
// 297.380 us; speedup vs baseline: 2.1345x; 1.0592x over previous
//
#include <hip/hip_runtime.h>
#include <math.h>

// ---------------------------------------------------------------------------
// SharedAttentionProcessor: B=4, H=20, S=1024, C=1280, hd=64
// R5: attn 40KB LDS (K dbuf + V single + P) -> 4 blocks/CU; uniform 8-kt
// slices (grid 8x20x12, bf16 O-partials); denominator via ones-MFMA
// (C-layout, no shuffles); fused converts; vectorized stats/adain.
// ---------------------------------------------------------------------------

typedef __bf16 bf16x8 __attribute__((ext_vector_type(8)));
typedef float f32x4 __attribute__((ext_vector_type(4)));
typedef unsigned short u16x8 __attribute__((ext_vector_type(8)));

#define BDIM 256

__device__ inline unsigned short f2bf(float f) {
  unsigned int u = __float_as_uint(f);
  u += 0x7fffu + ((u >> 16) & 1u);   // RNE (inputs finite)
  return (unsigned short)(u >> 16);
}
__device__ inline unsigned int pack_bf2(float lo, float hi) {
  return (unsigned int)f2bf(lo) | ((unsigned int)f2bf(hi) << 16);
}
__device__ inline float bf2f(unsigned short h) {
  return __uint_as_float(((unsigned int)h) << 16);
}

__device__ inline void gl_lds16(const unsigned short* g, unsigned short* l) {
  __builtin_amdgcn_global_load_lds(
      (const __attribute__((address_space(1))) unsigned int*)g,
      (__attribute__((address_space(3))) unsigned int*)l, 16, 0, 0);
}

// --------------------------- fused fp32 -> bf16 convert ---------------------
// X (1,310,720 float4) then Wq,Wk,Wv,Wo (409,600 float4 each). 11520 blocks.
__global__ __launch_bounds__(BDIM) void k_convert_all(
    const float* __restrict__ X, const float* __restrict__ Wq,
    const float* __restrict__ Wk, const float* __restrict__ Wv,
    const float* __restrict__ Wo, unsigned short* __restrict__ Xbf,
    unsigned short* __restrict__ Wcat, unsigned short* __restrict__ Wobf) {
  const int idx = blockIdx.x * BDIM + threadIdx.x;
  const float* src;
  unsigned short* dst;
  int off;
  if (idx < 1310720) {
    src = X; dst = Xbf; off = idx;
  } else {
    const int r = idx - 1310720;
    const int which = r / 409600;
    off = r - which * 409600;
    src = (which == 0) ? Wq : (which == 1) ? Wk : (which == 2) ? Wv : Wo;
    dst = (which < 3) ? Wcat + (size_t)which * 1638400 : Wobf;
  }
  const float4 v = ((const float4*)src)[off];
  ushort4 o;
  o.x = f2bf(v.x); o.y = f2bf(v.y); o.z = f2bf(v.z); o.w = f2bf(v.w);
  ((ushort4*)dst)[off] = o;
}

// --------------------------- bf16 GEMM 128x128 (QKV) ------------------------
__global__ __launch_bounds__(BDIM) void k_gemm_bf16(
    const unsigned short* __restrict__ A, const unsigned short* __restrict__ B,
    unsigned short* __restrict__ Cbf, int M, int N, int K) {
  __shared__ unsigned short As[128 * 32];
  __shared__ unsigned short Bs[128 * 32];
  const int t = threadIdx.x;
  const int w = t >> 6, lane = t & 63, quad = lane >> 4, l16 = lane & 15;
  const int wm = (w >> 1) << 6, wn = (w & 1) << 6;
  const int mBase = blockIdx.x * 128, nBase = blockIdx.y * 128;

  f32x4 acc[4][4];
#pragma unroll
  for (int i = 0; i < 4; i++)
#pragma unroll
    for (int j = 0; j < 4; j++) acc[i][j] = (f32x4){0.f, 0.f, 0.f, 0.f};

  const int r0 = t >> 2;
  const int kk0 = (t & 3) * 8;

  for (int k0 = 0; k0 < K; k0 += 32) {
    gl_lds16(A + (size_t)(mBase + r0) * K + k0 + kk0, As + t * 8);
    gl_lds16(A + (size_t)(mBase + 64 + r0) * K + k0 + kk0, As + (t + 256) * 8);
    gl_lds16(B + (size_t)(nBase + r0) * K + k0 + kk0, Bs + t * 8);
    gl_lds16(B + (size_t)(nBase + 64 + r0) * K + k0 + kk0, Bs + (t + 256) * 8);
    __syncthreads();
    bf16x8 af[4], bfr[4];
#pragma unroll
    for (int i = 0; i < 4; i++)
      af[i] = *(const bf16x8*)(As + (wm + i * 16 + l16) * 32 + quad * 8);
#pragma unroll
    for (int i = 0; i < 4; i++)
      bfr[i] = *(const bf16x8*)(Bs + (wn + i * 16 + l16) * 32 + quad * 8);
#pragma unroll
    for (int mi = 0; mi < 4; mi++)
#pragma unroll
      for (int ni = 0; ni < 4; ni++)
        acc[mi][ni] = __builtin_amdgcn_mfma_f32_16x16x32_bf16(
            af[mi], bfr[ni], acc[mi][ni], 0, 0, 0);
    __syncthreads();
  }

#pragma unroll
  for (int mi = 0; mi < 4; mi++)
#pragma unroll
    for (int r = 0; r < 4; r++) {
      const int row = mBase + wm + mi * 16 + quad * 4 + r;
#pragma unroll
      for (int ni = 0; ni < 4; ni++)
        Cbf[(size_t)row * N + nBase + wn + ni * 16 + l16] = f2bf(acc[mi][ni][r]);
    }
}

// --------------------------- bf16 GEMM 64x128 (out proj) --------------------
__global__ __launch_bounds__(BDIM) void k_gemm_64x128(
    const unsigned short* __restrict__ A, const unsigned short* __restrict__ B,
    float* __restrict__ Cf, const float* __restrict__ bias, int M, int N,
    int K) {
  __shared__ unsigned short As[64 * 32];
  __shared__ unsigned short Bs[128 * 32];
  const int t = threadIdx.x;
  const int w = t >> 6, lane = t & 63, quad = lane >> 4, l16 = lane & 15;
  const int wm = (w >> 1) << 5, wn = (w & 1) << 6;
  const int mBase = blockIdx.x * 64, nBase = blockIdx.y * 128;

  f32x4 acc[2][4];
#pragma unroll
  for (int i = 0; i < 2; i++)
#pragma unroll
    for (int j = 0; j < 4; j++) acc[i][j] = (f32x4){0.f, 0.f, 0.f, 0.f};

  const int r0 = t >> 2;
  const int kk0 = (t & 3) * 8;

  for (int k0 = 0; k0 < K; k0 += 32) {
    gl_lds16(A + (size_t)(mBase + r0) * K + k0 + kk0, As + t * 8);
    gl_lds16(B + (size_t)(nBase + r0) * K + k0 + kk0, Bs + t * 8);
    gl_lds16(B + (size_t)(nBase + 64 + r0) * K + k0 + kk0, Bs + (t + 256) * 8);
    __syncthreads();
    bf16x8 af[2], bfr[4];
#pragma unroll
    for (int i = 0; i < 2; i++)
      af[i] = *(const bf16x8*)(As + (wm + i * 16 + l16) * 32 + quad * 8);
#pragma unroll
    for (int i = 0; i < 4; i++)
      bfr[i] = *(const bf16x8*)(Bs + (wn + i * 16 + l16) * 32 + quad * 8);
#pragma unroll
    for (int mi = 0; mi < 2; mi++)
#pragma unroll
      for (int ni = 0; ni < 4; ni++)
        acc[mi][ni] = __builtin_amdgcn_mfma_f32_16x16x32_bf16(
            af[mi], bfr[ni], acc[mi][ni], 0, 0, 0);
    __syncthreads();
  }

#pragma unroll
  for (int mi = 0; mi < 2; mi++)
#pragma unroll
    for (int r = 0; r < 4; r++) {
      const int row = mBase + wm + mi * 16 + quad * 4 + r;
#pragma unroll
      for (int ni = 0; ni < 4; ni++) {
        const int col = nBase + wn + ni * 16 + l16;
        Cf[(size_t)row * N + col] = acc[mi][ni][r] + bias[col];
      }
    }
}

// --------------------------- adain stats (two-stage) ------------------------
// stage 1: 32-row chunks, ushort4 per thread. grid (32, 8), block 320.
__global__ __launch_bounds__(320) void k_stats1(
    const unsigned short* __restrict__ QKV, float* __restrict__ psum,
    float* __restrict__ psq) {
  const int z = blockIdx.y, which = z >> 2, b = z & 3;
  const int c = threadIdx.x * 4;
  const size_t base =
      (size_t)(b * 1024 + blockIdx.x * 32) * 3840 + which * 1280 + c;
  float4 s = {0.f, 0.f, 0.f, 0.f}, s2 = {0.f, 0.f, 0.f, 0.f};
#pragma unroll 8
  for (int i = 0; i < 32; ++i) {
    const ushort4 xv = *(const ushort4*)(QKV + base + (size_t)i * 3840);
    const float x0 = bf2f(xv.x), x1 = bf2f(xv.y), x2 = bf2f(xv.z),
                x3 = bf2f(xv.w);
    s.x += x0; s.y += x1; s.z += x2; s.w += x3;
    s2.x = fmaf(x0, x0, s2.x); s2.y = fmaf(x1, x1, s2.y);
    s2.z = fmaf(x2, x2, s2.z); s2.w = fmaf(x3, x3, s2.w);
  }
  const size_t o = ((size_t)z * 32 + blockIdx.x) * 1280 + c;
  *(float4*)(psum + o) = s;
  *(float4*)(psq + o) = s2;
}

// stage 2: reduce 32 partials. grid (5, 8), block 256.
__global__ __launch_bounds__(BDIM) void k_stats2(
    const float* __restrict__ psum, const float* __restrict__ psq,
    float* __restrict__ stats) {
  const int z = blockIdx.y, which = z >> 2, b = z & 3;
  const int c = blockIdx.x * 256 + threadIdx.x;
  float s = 0.f, s2 = 0.f;
#pragma unroll
  for (int j = 0; j < 32; ++j) {
    s += psum[((size_t)z * 32 + j) * 1280 + c];
    s2 += psq[((size_t)z * 32 + j) * 1280 + c];
  }
  const float mean = s * (1.0f / 1024.0f);
  const float var = (s2 - 1024.0f * mean * mean) * (1.0f / 1023.0f);
  stats[((which * 2 + 0) * 4 + b) * 1280 + c] = mean;
  stats[((which * 2 + 1) * 4 + b) * 1280 + c] = sqrtf(var + 1e-5f);
}

// --------------------------- adain apply (x4 vectorized) --------------------
// grid (1280, 4, 2): y=b, z=which; idx -> (s, c4)
__global__ __launch_bounds__(BDIM) void k_adain(
    const unsigned short* __restrict__ QKV, const float* __restrict__ stats,
    unsigned short* __restrict__ qn, unsigned short* __restrict__ kn) {
  const int which = blockIdx.z, b = blockIdx.y;
  const int idx = blockIdx.x * BDIM + threadIdx.x;  // [0, 327680)
  const int s = idx / 320;
  const int c = (idx - s * 320) * 4;
  const int sb = (b < 2) ? 0 : 2;
  const ushort4 xv =
      *(const ushort4*)(QKV + ((size_t)(b * 1024 + s)) * 3840 + which * 1280 + c);
  const float4 mean = *(const float4*)(stats + ((which * 2 + 0) * 4 + b) * 1280 + c);
  const float4 stdv = *(const float4*)(stats + ((which * 2 + 1) * 4 + b) * 1280 + c);
  const float4 meanS = *(const float4*)(stats + ((which * 2 + 0) * 4 + sb) * 1280 + c);
  const float4 stdS = *(const float4*)(stats + ((which * 2 + 1) * 4 + sb) * 1280 + c);
  ushort4 o;
  o.x = f2bf((bf2f(xv.x) - mean.x) / stdv.x * stdS.x + meanS.x);
  o.y = f2bf((bf2f(xv.y) - mean.y) / stdv.y * stdS.y + meanS.y);
  o.z = f2bf((bf2f(xv.z) - mean.z) / stdv.z * stdS.z + meanS.z);
  o.w = f2bf((bf2f(xv.w) - mean.w) / stdv.w * stdS.w + meanS.w);
  unsigned short* dst = (which == 0) ? qn : kn;
  *(ushort4*)(dst + ((size_t)(b * 1024 + s)) * 1280 + c) = o;
}

// --------------------------- V transpose ------------------------------------
__global__ __launch_bounds__(BDIM) void k_transpose_v(
    const unsigned short* __restrict__ QKV, unsigned short* __restrict__ vt) {
  __shared__ unsigned short tile[64][65];
  const int s0 = blockIdx.x * 64, c0 = blockIdx.y * 64, b = blockIdx.z;
  const int t = threadIdx.x;
  const int r = t >> 2, seg = (t & 3) * 16;
  const size_t goff = ((size_t)(b * 1024 + s0 + r)) * 3840 + 2560 + c0 + seg;
  const u16x8 va = *(const u16x8*)(QKV + goff);
  const u16x8 vb = *(const u16x8*)(QKV + goff + 8);
#pragma unroll
  for (int j = 0; j < 8; j++) {
    tile[r][seg + j] = va[j];
    tile[r][seg + 8 + j] = vb[j];
  }
  __syncthreads();
  u16x8 o0, o1;
#pragma unroll
  for (int j = 0; j < 8; j++) {
    o0[j] = tile[seg + j][r];
    o1[j] = tile[seg + 8 + j][r];
  }
  const size_t ooff = ((size_t)(b * 1280 + c0 + r)) * 1024 + s0 + seg;
  *(u16x8*)(vt + ooff) = o0;
  *(u16x8*)(vt + ooff + 8) = o1;
}

// --------------------------- flash attention --------------------------------
// grid (8, 20, 12): z -> (b, chunk); every block runs exactly 8 key-tiles.
// b0: z 0-1 (2 slices), b1: z 2-5 (4), b2: z 6-7 (2), b3: z 8-11 (4).
// Even b: style==self -> plain softmax over own 1024 keys (factor 3 cancels).
// Odd b: 32 kt total (16 own + 16 style w/ +log2 bias), 4 chunks.
// LDS 40 KB: K double-buffered, V single (staged under QK+exp), P swizzled.
// Denominator accumulated by mfma(P, ones) -> C-layout, no shuffles.
// Outputs bf16 O-partials + fp32 L-partials; k_combine merges.
__global__ __launch_bounds__(BDIM, 4) void k_attn(
    const unsigned short* __restrict__ qn, const unsigned short* __restrict__ kn,
    const unsigned short* __restrict__ vt, unsigned short* __restrict__ Opart,
    float* __restrict__ Lpart) {
  const int S = 1024, C = 1280;
  const int qt = blockIdx.x, h = blockIdx.y, zs = blockIdx.z;
  int b, chunk;
  if (zs < 2)      { b = 0; chunk = zs; }
  else if (zs < 6) { b = 1; chunk = zs - 2; }
  else if (zs < 8) { b = 2; chunk = zs - 6; }
  else             { b = 3; chunk = zs - 8; }
  const int ktBeg = chunk * 8;
  const int t = threadIdx.x, w = t >> 6, lane = t & 63;
  const int quad = lane >> 4, l16 = lane & 15;
  const int bstyle = (b < 2) ? 0 : 2;
  const int qrow = qt * 128 + w * 32;

  __shared__ unsigned short Ks[2][2][64 * 32];  // [buf][dim-half] 16 KB
  __shared__ unsigned short Vs[2][64 * 32];     // [key-half]       8 KB
  __shared__ unsigned short Plds[4][32][64];    // swizzled        16 KB

  bf16x8 aq[2][2];
#pragma unroll
  for (int g = 0; g < 2; ++g) {
    const size_t qoff =
        ((size_t)(b * S + qrow + g * 16 + l16)) * C + h * 64 + quad * 8;
    aq[g][0] = *(const bf16x8*)(qn + qoff);
    aq[g][1] = *(const bf16x8*)(qn + qoff + 32);
  }

  bf16x8 ones;
#pragma unroll
  for (int i = 0; i < 8; ++i) ones[i] = (__bf16)1.0f;

  f32x4 o[2][4], lsum[2];
#pragma unroll
  for (int g = 0; g < 2; ++g) {
    lsum[g] = (f32x4){0.f, 0.f, 0.f, 0.f};
#pragma unroll
    for (int i = 0; i < 4; i++) o[g][i] = (f32x4){0.f, 0.f, 0.f, 0.f};
  }

  const int krow = t >> 2;
  const int kseg = (t & 3) * 8;
  const int sw = l16 & 14;  // P-granule XOR swizzle

  auto stageK = [&](int buf, int kt) {
    const int bs = (kt < 16) ? b : bstyle;
    const int sk = (kt & 15) * 64;
    const unsigned short* kg =
        kn + (size_t)(bs * S + sk + krow) * C + h * 64 + kseg;
    gl_lds16(kg, Ks[buf][0] + t * 8);
    gl_lds16(kg + 32, Ks[buf][1] + t * 8);
  };
  auto stageV = [&](int kt) {
    const int bs = (kt < 16) ? b : bstyle;
    const int sk = (kt & 15) * 64;
    const unsigned short* vg =
        vt + (size_t)(bs * C + h * 64 + krow) * S + sk + kseg;
    gl_lds16(vg, Vs[0] + t * 8);
    gl_lds16(vg + 32, Vs[1] + t * 8);
  };

  stageK(0, ktBeg);

  const float SCALE2 = 0.125f * 1.44269504088896341f;

  for (int i = 0; i < 8; ++i) {
    const int kt = ktBeg + i;
    const int buf = i & 1;
    __syncthreads();  // K[buf] staged; prior V/P reads complete
    stageV(kt);
    if (i + 1 < 8) stageK(buf ^ 1, kt + 1);

    const float bias2 = (kt >= 16) ? 1.0f : 0.0f;

    // S^T: D[m=key (nt*16+quad*4+r)][n=query l16]
    f32x4 z2[2][4];
#pragma unroll
    for (int nt = 0; nt < 4; ++nt) {
      const bf16x8 bk0 =
          *(const bf16x8*)(Ks[buf][0] + (nt * 16 + l16) * 32 + quad * 8);
      const bf16x8 bk1 =
          *(const bf16x8*)(Ks[buf][1] + (nt * 16 + l16) * 32 + quad * 8);
#pragma unroll
      for (int g = 0; g < 2; ++g) {
        f32x4 zz = (f32x4){0.f, 0.f, 0.f, 0.f};
        zz = __builtin_amdgcn_mfma_f32_16x16x32_bf16(bk0, aq[g][0], zz, 0, 0, 0);
        zz = __builtin_amdgcn_mfma_f32_16x16x32_bf16(bk1, aq[g][1], zz, 0, 0, 0);
        z2[g][nt] = zz;
      }
    }

    // exp2, pack 4 keys -> one swizzled b64 write
#pragma unroll
    for (int g = 0; g < 2; ++g) {
#pragma unroll
      for (int nt = 0; nt < 4; ++nt) {
        const float e0 = exp2f(fmaf(z2[g][nt][0], SCALE2, bias2));
        const float e1 = exp2f(fmaf(z2[g][nt][1], SCALE2, bias2));
        const float e2 = exp2f(fmaf(z2[g][nt][2], SCALE2, bias2));
        const float e3 = exp2f(fmaf(z2[g][nt][3], SCALE2, bias2));
        uint2 pk;
        pk.x = pack_bf2(e0, e1);
        pk.y = pack_bf2(e2, e3);
        const int phys = (nt * 4 + quad) ^ sw;
        *(uint2*)(&Plds[w][g * 16 + l16][phys * 4]) = pk;
      }
    }

    __syncthreads();  // V staged (vmcnt drained before barrier)

    // lsum += P*1 ; O += P*V^T
#pragma unroll
    for (int g = 0; g < 2; ++g) {
      const int a0 = (2 * quad) ^ sw;
      const int a1 = (2 * quad + 8) ^ sw;
      const bf16x8 pa0 = *(const bf16x8*)(&Plds[w][g * 16 + l16][a0 * 4]);
      const bf16x8 pa1 = *(const bf16x8*)(&Plds[w][g * 16 + l16][a1 * 4]);
      lsum[g] = __builtin_amdgcn_mfma_f32_16x16x32_bf16(pa0, ones, lsum[g], 0, 0, 0);
      lsum[g] = __builtin_amdgcn_mfma_f32_16x16x32_bf16(pa1, ones, lsum[g], 0, 0, 0);
#pragma unroll
      for (int dt = 0; dt < 4; ++dt) {
        const bf16x8 vb0 =
            *(const bf16x8*)(Vs[0] + (dt * 16 + l16) * 32 + quad * 8);
        const bf16x8 vb1 =
            *(const bf16x8*)(Vs[1] + (dt * 16 + l16) * 32 + quad * 8);
        o[g][dt] =
            __builtin_amdgcn_mfma_f32_16x16x32_bf16(pa0, vb0, o[g][dt], 0, 0, 0);
        o[g][dt] =
            __builtin_amdgcn_mfma_f32_16x16x32_bf16(pa1, vb1, o[g][dt], 0, 0, 0);
      }
    }
  }

  // lsum is C-layout: row q = g*16+quad*4+r, all 16 cols equal.
  if (l16 == 0) {
#pragma unroll
    for (int g = 0; g < 2; ++g)
#pragma unroll
      for (int r = 0; r < 4; ++r)
        Lpart[((size_t)zs * 20 + h) * 1024 + qrow + g * 16 + quad * 4 + r] =
            lsum[g][r];
  }

  unsigned short* Op = Opart + (size_t)zs * 1024 * 1280;
#pragma unroll
  for (int g = 0; g < 2; ++g)
#pragma unroll
    for (int dt = 0; dt < 4; ++dt)
#pragma unroll
      for (int r = 0; r < 4; ++r)
        Op[(size_t)(qrow + g * 16 + quad * 4 + r) * 1280 + h * 64 + dt * 16 +
           l16] = f2bf(o[g][dt][r]);
}

// --------------------------- combine slice partials -------------------------
// 2560 blocks x 256 thr, 8 elems (ushort8) per thread.
__global__ __launch_bounds__(BDIM) void k_combine(
    const unsigned short* __restrict__ Opart, const float* __restrict__ Lpart,
    unsigned short* __restrict__ attnb) {
  const int idx = blockIdx.x * BDIM + threadIdx.x;  // [0, 655360)
  const int row = idx / 160;
  const int c = (idx - row * 160) * 8;
  const int b = row >> 10, q = row & 1023, h = c >> 6;
  const int zb = (b >> 1) * 6 + (b & 1) * 2;  // 0,2,6,8
  const int ns = 2 + (b & 1) * 2;             // 2 or 4 slices
  float L = 0.f;
  float acc[8] = {0.f, 0.f, 0.f, 0.f, 0.f, 0.f, 0.f, 0.f};
  for (int s = 0; s < ns; ++s) {
    L += Lpart[((size_t)(zb + s) * 20 + h) * 1024 + q];
    const u16x8 v =
        *(const u16x8*)(Opart + (size_t)(zb + s) * 1310720 + (size_t)q * 1280 + c);
#pragma unroll
    for (int j = 0; j < 8; ++j) acc[j] += bf2f(v[j]);
  }
  const float rl = 1.0f / L;
  u16x8 o8;
#pragma unroll
  for (int j = 0; j < 8; ++j) o8[j] = f2bf(acc[j] * rl);
  *(u16x8*)(attnb + (size_t)row * 1280 + c) = o8;
}

// ---------------------------------------------------------------------------
extern "C" void kernel_launch(void* const* d_in, const int* in_sizes, int n_in,
                              void* d_out, int out_size, void* d_ws,
                              size_t ws_size, hipStream_t stream) {
  const float* X = (const float*)d_in[0];
  const float* Wq = (const float*)d_in[1];
  const float* Wk = (const float*)d_in[2];
  const float* Wv = (const float*)d_in[3];
  const float* Wo = (const float*)d_in[4];
  const float* bo = (const float*)d_in[5];
  float* out = (float*)d_out;

  char* ws = (char*)d_ws;
  size_t off = 0;
  auto alloc = [&](size_t bytes) {
    char* p = ws + off;
    off += (bytes + 255) & ~(size_t)255;
    return p;
  };
  // Aliases (lifetimes disjoint): Opart(bf16, 31.5MB) <- QKV region (exact);
  // Lpart(0.98MB) <- Wcat; psum/psq(1.3MB each) <- attnb region.
  unsigned short* Wcat = (unsigned short*)alloc(3840ull * 1280 * 2);
  unsigned short* Xbf = (unsigned short*)alloc(4096ull * 1280 * 2);
  unsigned short* QKV = (unsigned short*)alloc(4096ull * 3840 * 2);
  unsigned short* Wobf = (unsigned short*)alloc(1280ull * 1280 * 2);
  float* stats = (float*)alloc(2ull * 2 * 4 * 1280 * 4);
  unsigned short* qnb = (unsigned short*)alloc(4096ull * 1280 * 2);
  unsigned short* knb = (unsigned short*)alloc(4096ull * 1280 * 2);
  unsigned short* vtb = (unsigned short*)alloc(4096ull * 1280 * 2);
  unsigned short* attnb = (unsigned short*)alloc(4096ull * 1280 * 2);

  unsigned short* Opart = QKV;                        // 12 x 1024 x 1280 bf16
  float* Lpart = (float*)Wcat;                        // 12 x 20 x 1024 fp32
  float* psum = (float*)attnb;                        // 8 x 32 x 1280 fp32
  float* psq = (float*)(attnb + 4096ull * 1280 / 2);  // second half

  k_convert_all<<<11520, BDIM, 0, stream>>>(X, Wq, Wk, Wv, Wo, Xbf, Wcat, Wobf);
  k_gemm_bf16<<<dim3(32, 30), BDIM, 0, stream>>>(Xbf, Wcat, QKV, 4096, 3840,
                                                 1280);
  k_stats1<<<dim3(32, 8), 320, 0, stream>>>(QKV, psum, psq);
  k_stats2<<<dim3(5, 8), BDIM, 0, stream>>>(psum, psq, stats);
  k_adain<<<dim3(1280, 4, 2), BDIM, 0, stream>>>(QKV, stats, qnb, knb);
  k_transpose_v<<<dim3(16, 20, 4), BDIM, 0, stream>>>(QKV, vtb);
  k_attn<<<dim3(8, 20, 12), BDIM, 0, stream>>>(qnb, knb, vtb, Opart, Lpart);
  k_combine<<<2560, BDIM, 0, stream>>>(Opart, Lpart, attnb);
  k_gemm_64x128<<<dim3(64, 10), BDIM, 0, stream>>>(attnb, Wobf, out, bo, 4096,
                                                   1280, 1280);
}

// Round 6
// 288.606 us; speedup vs baseline: 2.1994x; 1.0304x over previous
//
#include <hip/hip_runtime.h>
#include <math.h>

// ---------------------------------------------------------------------------
// SharedAttentionProcessor: B=4, H=20, S=1024, C=1280, hd=64
// R6: BK=64 GEMMs (half the barrier drains, 32 MFMA/barrier); attention with
// single barrier per K-tile (K+V double-buffered, prefetch spans the whole
// iteration); adain+transpose merged into one launch.
// ---------------------------------------------------------------------------

typedef __bf16 bf16x8 __attribute__((ext_vector_type(8)));
typedef float f32x4 __attribute__((ext_vector_type(4)));
typedef unsigned short u16x8 __attribute__((ext_vector_type(8)));

#define BDIM 256

__device__ inline unsigned short f2bf(float f) {
  unsigned int u = __float_as_uint(f);
  u += 0x7fffu + ((u >> 16) & 1u);   // RNE (inputs finite)
  return (unsigned short)(u >> 16);
}
__device__ inline unsigned int pack_bf2(float lo, float hi) {
  return (unsigned int)f2bf(lo) | ((unsigned int)f2bf(hi) << 16);
}
__device__ inline float bf2f(unsigned short h) {
  return __uint_as_float(((unsigned int)h) << 16);
}

__device__ inline void gl_lds16(const unsigned short* g, unsigned short* l) {
  __builtin_amdgcn_global_load_lds(
      (const __attribute__((address_space(1))) unsigned int*)g,
      (__attribute__((address_space(3))) unsigned int*)l, 16, 0, 0);
}

// --------------------------- fused fp32 -> bf16 convert ---------------------
__global__ __launch_bounds__(BDIM) void k_convert_all(
    const float* __restrict__ X, const float* __restrict__ Wq,
    const float* __restrict__ Wk, const float* __restrict__ Wv,
    const float* __restrict__ Wo, unsigned short* __restrict__ Xbf,
    unsigned short* __restrict__ Wcat, unsigned short* __restrict__ Wobf) {
  const int idx = blockIdx.x * BDIM + threadIdx.x;
  const float* src;
  unsigned short* dst;
  int off;
  if (idx < 1310720) {
    src = X; dst = Xbf; off = idx;
  } else {
    const int r = idx - 1310720;
    const int which = r / 409600;
    off = r - which * 409600;
    src = (which == 0) ? Wq : (which == 1) ? Wk : (which == 2) ? Wv : Wo;
    dst = (which < 3) ? Wcat + (size_t)which * 1638400 : Wobf;
  }
  const float4 v = ((const float4*)src)[off];
  ushort4 o;
  o.x = f2bf(v.x); o.y = f2bf(v.y); o.z = f2bf(v.z); o.w = f2bf(v.w);
  ((ushort4*)dst)[off] = o;
}

// --------------------------- bf16 GEMM 128x128, BK=64 (QKV) -----------------
// A [M,K], B [N,K] row-major bf16 -> C = A @ B^T (bf16). Split-half staging
// keeps 64B LDS rows (proven conflict level) + gl_lds contiguity.
__global__ __launch_bounds__(BDIM) void k_gemm_bf16(
    const unsigned short* __restrict__ A, const unsigned short* __restrict__ B,
    unsigned short* __restrict__ Cbf, int M, int N, int K) {
  __shared__ unsigned short As[2][128 * 32];
  __shared__ unsigned short Bs[2][128 * 32];
  const int t = threadIdx.x;
  const int w = t >> 6, lane = t & 63, quad = lane >> 4, l16 = lane & 15;
  const int wm = (w >> 1) << 6, wn = (w & 1) << 6;
  const int mBase = blockIdx.x * 128, nBase = blockIdx.y * 128;

  f32x4 acc[4][4];
#pragma unroll
  for (int i = 0; i < 4; i++)
#pragma unroll
    for (int j = 0; j < 4; j++) acc[i][j] = (f32x4){0.f, 0.f, 0.f, 0.f};

  const int r0 = t >> 2;
  const int kk0 = (t & 3) * 8;

  for (int k0 = 0; k0 < K; k0 += 64) {
    const unsigned short* Ab = A + (size_t)(mBase + r0) * K + k0 + kk0;
    const unsigned short* Bb = B + (size_t)(nBase + r0) * K + k0 + kk0;
    gl_lds16(Ab, As[0] + t * 8);
    gl_lds16(Ab + (size_t)64 * K, As[0] + (t + 256) * 8);
    gl_lds16(Ab + 32, As[1] + t * 8);
    gl_lds16(Ab + (size_t)64 * K + 32, As[1] + (t + 256) * 8);
    gl_lds16(Bb, Bs[0] + t * 8);
    gl_lds16(Bb + (size_t)64 * K, Bs[0] + (t + 256) * 8);
    gl_lds16(Bb + 32, Bs[1] + t * 8);
    gl_lds16(Bb + (size_t)64 * K + 32, Bs[1] + (t + 256) * 8);
    __syncthreads();
    bf16x8 af[2][4], bfr[2][4];
#pragma unroll
    for (int hh = 0; hh < 2; hh++)
#pragma unroll
      for (int i = 0; i < 4; i++) {
        af[hh][i] = *(const bf16x8*)(As[hh] + (wm + i * 16 + l16) * 32 + quad * 8);
        bfr[hh][i] = *(const bf16x8*)(Bs[hh] + (wn + i * 16 + l16) * 32 + quad * 8);
      }
#pragma unroll
    for (int hh = 0; hh < 2; hh++)
#pragma unroll
      for (int mi = 0; mi < 4; mi++)
#pragma unroll
        for (int ni = 0; ni < 4; ni++)
          acc[mi][ni] = __builtin_amdgcn_mfma_f32_16x16x32_bf16(
              af[hh][mi], bfr[hh][ni], acc[mi][ni], 0, 0, 0);
    __syncthreads();
  }

#pragma unroll
  for (int mi = 0; mi < 4; mi++)
#pragma unroll
    for (int r = 0; r < 4; r++) {
      const int row = mBase + wm + mi * 16 + quad * 4 + r;
#pragma unroll
      for (int ni = 0; ni < 4; ni++)
        Cbf[(size_t)row * N + nBase + wn + ni * 16 + l16] = f2bf(acc[mi][ni][r]);
    }
}

// --------------------------- bf16 GEMM 64x128, BK=64 (out proj) -------------
__global__ __launch_bounds__(BDIM) void k_gemm_64x128(
    const unsigned short* __restrict__ A, const unsigned short* __restrict__ B,
    float* __restrict__ Cf, const float* __restrict__ bias, int M, int N,
    int K) {
  __shared__ unsigned short As[2][64 * 32];
  __shared__ unsigned short Bs[2][128 * 32];
  const int t = threadIdx.x;
  const int w = t >> 6, lane = t & 63, quad = lane >> 4, l16 = lane & 15;
  const int wm = (w >> 1) << 5, wn = (w & 1) << 6;
  const int mBase = blockIdx.x * 64, nBase = blockIdx.y * 128;

  f32x4 acc[2][4];
#pragma unroll
  for (int i = 0; i < 2; i++)
#pragma unroll
    for (int j = 0; j < 4; j++) acc[i][j] = (f32x4){0.f, 0.f, 0.f, 0.f};

  const int r0 = t >> 2;
  const int kk0 = (t & 3) * 8;

  for (int k0 = 0; k0 < K; k0 += 64) {
    const unsigned short* Ab = A + (size_t)(mBase + r0) * K + k0 + kk0;
    const unsigned short* Bb = B + (size_t)(nBase + r0) * K + k0 + kk0;
    gl_lds16(Ab, As[0] + t * 8);
    gl_lds16(Ab + 32, As[1] + t * 8);
    gl_lds16(Bb, Bs[0] + t * 8);
    gl_lds16(Bb + (size_t)64 * K, Bs[0] + (t + 256) * 8);
    gl_lds16(Bb + 32, Bs[1] + t * 8);
    gl_lds16(Bb + (size_t)64 * K + 32, Bs[1] + (t + 256) * 8);
    __syncthreads();
    bf16x8 af[2][2], bfr[2][4];
#pragma unroll
    for (int hh = 0; hh < 2; hh++) {
#pragma unroll
      for (int i = 0; i < 2; i++)
        af[hh][i] = *(const bf16x8*)(As[hh] + (wm + i * 16 + l16) * 32 + quad * 8);
#pragma unroll
      for (int i = 0; i < 4; i++)
        bfr[hh][i] = *(const bf16x8*)(Bs[hh] + (wn + i * 16 + l16) * 32 + quad * 8);
    }
#pragma unroll
    for (int hh = 0; hh < 2; hh++)
#pragma unroll
      for (int mi = 0; mi < 2; mi++)
#pragma unroll
        for (int ni = 0; ni < 4; ni++)
          acc[mi][ni] = __builtin_amdgcn_mfma_f32_16x16x32_bf16(
              af[hh][mi], bfr[hh][ni], acc[mi][ni], 0, 0, 0);
    __syncthreads();
  }

#pragma unroll
  for (int mi = 0; mi < 2; mi++)
#pragma unroll
    for (int r = 0; r < 4; r++) {
      const int row = mBase + wm + mi * 16 + quad * 4 + r;
#pragma unroll
      for (int ni = 0; ni < 4; ni++) {
        const int col = nBase + wn + ni * 16 + l16;
        Cf[(size_t)row * N + col] = acc[mi][ni][r] + bias[col];
      }
    }
}

// --------------------------- adain stats (two-stage) ------------------------
__global__ __launch_bounds__(320) void k_stats1(
    const unsigned short* __restrict__ QKV, float* __restrict__ psum,
    float* __restrict__ psq) {
  const int z = blockIdx.y, which = z >> 2, b = z & 3;
  const int c = threadIdx.x * 4;
  const size_t base =
      (size_t)(b * 1024 + blockIdx.x * 32) * 3840 + which * 1280 + c;
  float4 s = {0.f, 0.f, 0.f, 0.f}, s2 = {0.f, 0.f, 0.f, 0.f};
#pragma unroll 8
  for (int i = 0; i < 32; ++i) {
    const ushort4 xv = *(const ushort4*)(QKV + base + (size_t)i * 3840);
    const float x0 = bf2f(xv.x), x1 = bf2f(xv.y), x2 = bf2f(xv.z),
                x3 = bf2f(xv.w);
    s.x += x0; s.y += x1; s.z += x2; s.w += x3;
    s2.x = fmaf(x0, x0, s2.x); s2.y = fmaf(x1, x1, s2.y);
    s2.z = fmaf(x2, x2, s2.z); s2.w = fmaf(x3, x3, s2.w);
  }
  const size_t o = ((size_t)z * 32 + blockIdx.x) * 1280 + c;
  *(float4*)(psum + o) = s;
  *(float4*)(psq + o) = s2;
}

__global__ __launch_bounds__(BDIM) void k_stats2(
    const float* __restrict__ psum, const float* __restrict__ psq,
    float* __restrict__ stats) {
  const int z = blockIdx.y, which = z >> 2, b = z & 3;
  const int c = blockIdx.x * 256 + threadIdx.x;
  float s = 0.f, s2 = 0.f;
#pragma unroll
  for (int j = 0; j < 32; ++j) {
    s += psum[((size_t)z * 32 + j) * 1280 + c];
    s2 += psq[((size_t)z * 32 + j) * 1280 + c];
  }
  const float mean = s * (1.0f / 1024.0f);
  const float var = (s2 - 1024.0f * mean * mean) * (1.0f / 1023.0f);
  stats[((which * 2 + 0) * 4 + b) * 1280 + c] = mean;
  stats[((which * 2 + 1) * 4 + b) * 1280 + c] = sqrtf(var + 1e-5f);
}

// --------------------- adain apply + V transpose (merged) -------------------
// grid.x = 11520: [0,10240) adain over q/k; [10240,11520) V transpose.
__global__ __launch_bounds__(BDIM) void k_adain_vt(
    const unsigned short* __restrict__ QKV, const float* __restrict__ stats,
    unsigned short* __restrict__ qn, unsigned short* __restrict__ kn,
    unsigned short* __restrict__ vt) {
  __shared__ unsigned short tile[64][65];
  const int bx = blockIdx.x;
  if (bx < 10240) {
    const int which = bx / 5120;
    const int rem = bx - which * 5120;
    const int b = rem / 1280;
    const int xb = rem - b * 1280;
    const int idx = xb * BDIM + threadIdx.x;  // [0, 327680)
    const int s = idx / 320;
    const int c = (idx - s * 320) * 4;
    const int sb = (b < 2) ? 0 : 2;
    const ushort4 xv = *(const ushort4*)(QKV + ((size_t)(b * 1024 + s)) * 3840 +
                                         which * 1280 + c);
    const float4 mean =
        *(const float4*)(stats + ((which * 2 + 0) * 4 + b) * 1280 + c);
    const float4 stdv =
        *(const float4*)(stats + ((which * 2 + 1) * 4 + b) * 1280 + c);
    const float4 meanS =
        *(const float4*)(stats + ((which * 2 + 0) * 4 + sb) * 1280 + c);
    const float4 stdS =
        *(const float4*)(stats + ((which * 2 + 1) * 4 + sb) * 1280 + c);
    ushort4 o;
    o.x = f2bf((bf2f(xv.x) - mean.x) / stdv.x * stdS.x + meanS.x);
    o.y = f2bf((bf2f(xv.y) - mean.y) / stdv.y * stdS.y + meanS.y);
    o.z = f2bf((bf2f(xv.z) - mean.z) / stdv.z * stdS.z + meanS.z);
    o.w = f2bf((bf2f(xv.w) - mean.w) / stdv.w * stdS.w + meanS.w);
    unsigned short* dst = (which == 0) ? qn : kn;
    *(ushort4*)(dst + ((size_t)(b * 1024 + s)) * 1280 + c) = o;
  } else {
    const int tb = bx - 10240;           // [0,1280)
    const int b = tb / 320;
    const int r2 = tb - b * 320;
    const int c0 = (r2 / 16) * 64;
    const int s0 = (r2 & 15) * 64;
    const int t = threadIdx.x;
    const int r = t >> 2, seg = (t & 3) * 16;
    const size_t goff = ((size_t)(b * 1024 + s0 + r)) * 3840 + 2560 + c0 + seg;
    const u16x8 va = *(const u16x8*)(QKV + goff);
    const u16x8 vb = *(const u16x8*)(QKV + goff + 8);
#pragma unroll
    for (int j = 0; j < 8; j++) {
      tile[r][seg + j] = va[j];
      tile[r][seg + 8 + j] = vb[j];
    }
    __syncthreads();
    u16x8 o0, o1;
#pragma unroll
    for (int j = 0; j < 8; j++) {
      o0[j] = tile[seg + j][r];
      o1[j] = tile[seg + 8 + j][r];
    }
    const size_t ooff = ((size_t)(b * 1280 + c0 + r)) * 1024 + s0 + seg;
    *(u16x8*)(vt + ooff) = o0;
    *(u16x8*)(vt + ooff + 8) = o1;
  }
}

// --------------------------- flash attention --------------------------------
// grid (8, 20, 12): z -> (b, chunk); every block runs exactly 8 key-tiles.
// Single barrier per tile: K+V double-buffered (48 KB), next-tile stage
// issued right after the sync so the prefetch spans the whole iteration.
__global__ __launch_bounds__(BDIM, 3) void k_attn(
    const unsigned short* __restrict__ qn, const unsigned short* __restrict__ kn,
    const unsigned short* __restrict__ vt, unsigned short* __restrict__ Opart,
    float* __restrict__ Lpart) {
  const int S = 1024, C = 1280;
  const int qt = blockIdx.x, h = blockIdx.y, zs = blockIdx.z;
  int b, chunk;
  if (zs < 2)      { b = 0; chunk = zs; }
  else if (zs < 6) { b = 1; chunk = zs - 2; }
  else if (zs < 8) { b = 2; chunk = zs - 6; }
  else             { b = 3; chunk = zs - 8; }
  const int ktBeg = chunk * 8;
  const int t = threadIdx.x, w = t >> 6, lane = t & 63;
  const int quad = lane >> 4, l16 = lane & 15;
  const int bstyle = (b < 2) ? 0 : 2;
  const int qrow = qt * 128 + w * 32;

  __shared__ unsigned short Ks[2][2][64 * 32];  // 16 KB
  __shared__ unsigned short Vs[2][2][64 * 32];  // 16 KB
  __shared__ unsigned short Plds[4][32][64];    // 16 KB, XOR-swizzled

  bf16x8 aq[2][2];
#pragma unroll
  for (int g = 0; g < 2; ++g) {
    const size_t qoff =
        ((size_t)(b * S + qrow + g * 16 + l16)) * C + h * 64 + quad * 8;
    aq[g][0] = *(const bf16x8*)(qn + qoff);
    aq[g][1] = *(const bf16x8*)(qn + qoff + 32);
  }

  bf16x8 ones;
#pragma unroll
  for (int i = 0; i < 8; ++i) ones[i] = (__bf16)1.0f;

  f32x4 o[2][4], lsum[2];
#pragma unroll
  for (int g = 0; g < 2; ++g) {
    lsum[g] = (f32x4){0.f, 0.f, 0.f, 0.f};
#pragma unroll
    for (int i = 0; i < 4; i++) o[g][i] = (f32x4){0.f, 0.f, 0.f, 0.f};
  }

  const int krow = t >> 2;
  const int kseg = (t & 3) * 8;
  const int sw = l16 & 14;

  auto stage = [&](int buf, int kt) {
    const int bs = (kt < 16) ? b : bstyle;
    const int sk = (kt & 15) * 64;
    const unsigned short* kg =
        kn + (size_t)(bs * S + sk + krow) * C + h * 64 + kseg;
    gl_lds16(kg, Ks[buf][0] + t * 8);
    gl_lds16(kg + 32, Ks[buf][1] + t * 8);
    const unsigned short* vg =
        vt + (size_t)(bs * C + h * 64 + krow) * S + sk + kseg;
    gl_lds16(vg, Vs[buf][0] + t * 8);
    gl_lds16(vg + 32, Vs[buf][1] + t * 8);
  };

  stage(0, ktBeg);

  const float SCALE2 = 0.125f * 1.44269504088896341f;

  for (int i = 0; i < 8; ++i) {
    const int kt = ktBeg + i;
    const int buf = i & 1;
    __syncthreads();  // stage(buf) done; all reads of buf^1 finished
    if (i + 1 < 8) stage(buf ^ 1, kt + 1);

    const float bias2 = (kt >= 16) ? 1.0f : 0.0f;

    // S^T: D[m=key (nt*16+quad*4+r)][n=query l16]
    f32x4 z2[2][4];
#pragma unroll
    for (int nt = 0; nt < 4; ++nt) {
      const bf16x8 bk0 =
          *(const bf16x8*)(Ks[buf][0] + (nt * 16 + l16) * 32 + quad * 8);
      const bf16x8 bk1 =
          *(const bf16x8*)(Ks[buf][1] + (nt * 16 + l16) * 32 + quad * 8);
#pragma unroll
      for (int g = 0; g < 2; ++g) {
        f32x4 zz = (f32x4){0.f, 0.f, 0.f, 0.f};
        zz = __builtin_amdgcn_mfma_f32_16x16x32_bf16(bk0, aq[g][0], zz, 0, 0, 0);
        zz = __builtin_amdgcn_mfma_f32_16x16x32_bf16(bk1, aq[g][1], zz, 0, 0, 0);
        z2[g][nt] = zz;
      }
    }

    // exp2, pack 4 keys -> one swizzled b64 write (per-wave buffer, no sync)
#pragma unroll
    for (int g = 0; g < 2; ++g) {
#pragma unroll
      for (int nt = 0; nt < 4; ++nt) {
        const float e0 = exp2f(fmaf(z2[g][nt][0], SCALE2, bias2));
        const float e1 = exp2f(fmaf(z2[g][nt][1], SCALE2, bias2));
        const float e2 = exp2f(fmaf(z2[g][nt][2], SCALE2, bias2));
        const float e3 = exp2f(fmaf(z2[g][nt][3], SCALE2, bias2));
        uint2 pk;
        pk.x = pack_bf2(e0, e1);
        pk.y = pack_bf2(e2, e3);
        const int phys = (nt * 4 + quad) ^ sw;
        *(uint2*)(&Plds[w][g * 16 + l16][phys * 4]) = pk;
      }
    }

    // lsum += P*1 ; O += P*V^T
#pragma unroll
    for (int g = 0; g < 2; ++g) {
      const int a0 = (2 * quad) ^ sw;
      const int a1 = (2 * quad + 8) ^ sw;
      const bf16x8 pa0 = *(const bf16x8*)(&Plds[w][g * 16 + l16][a0 * 4]);
      const bf16x8 pa1 = *(const bf16x8*)(&Plds[w][g * 16 + l16][a1 * 4]);
      lsum[g] = __builtin_amdgcn_mfma_f32_16x16x32_bf16(pa0, ones, lsum[g], 0, 0, 0);
      lsum[g] = __builtin_amdgcn_mfma_f32_16x16x32_bf16(pa1, ones, lsum[g], 0, 0, 0);
#pragma unroll
      for (int dt = 0; dt < 4; ++dt) {
        const bf16x8 vb0 =
            *(const bf16x8*)(Vs[buf][0] + (dt * 16 + l16) * 32 + quad * 8);
        const bf16x8 vb1 =
            *(const bf16x8*)(Vs[buf][1] + (dt * 16 + l16) * 32 + quad * 8);
        o[g][dt] =
            __builtin_amdgcn_mfma_f32_16x16x32_bf16(pa0, vb0, o[g][dt], 0, 0, 0);
        o[g][dt] =
            __builtin_amdgcn_mfma_f32_16x16x32_bf16(pa1, vb1, o[g][dt], 0, 0, 0);
      }
    }
  }

  if (l16 == 0) {
#pragma unroll
    for (int g = 0; g < 2; ++g)
#pragma unroll
      for (int r = 0; r < 4; ++r)
        Lpart[((size_t)zs * 20 + h) * 1024 + qrow + g * 16 + quad * 4 + r] =
            lsum[g][r];
  }

  unsigned short* Op = Opart + (size_t)zs * 1024 * 1280;
#pragma unroll
  for (int g = 0; g < 2; ++g)
#pragma unroll
    for (int dt = 0; dt < 4; ++dt)
#pragma unroll
      for (int r = 0; r < 4; ++r)
        Op[(size_t)(qrow + g * 16 + quad * 4 + r) * 1280 + h * 64 + dt * 16 +
           l16] = f2bf(o[g][dt][r]);
}

// --------------------------- combine slice partials -------------------------
__global__ __launch_bounds__(BDIM) void k_combine(
    const unsigned short* __restrict__ Opart, const float* __restrict__ Lpart,
    unsigned short* __restrict__ attnb) {
  const int idx = blockIdx.x * BDIM + threadIdx.x;  // [0, 655360)
  const int row = idx / 160;
  const int c = (idx - row * 160) * 8;
  const int b = row >> 10, q = row & 1023, h = c >> 6;
  const int zb = (b >> 1) * 6 + (b & 1) * 2;  // 0,2,6,8
  const int ns = 2 + (b & 1) * 2;             // 2 or 4 slices
  float L = 0.f;
  float acc[8] = {0.f, 0.f, 0.f, 0.f, 0.f, 0.f, 0.f, 0.f};
  for (int s = 0; s < ns; ++s) {
    L += Lpart[((size_t)(zb + s) * 20 + h) * 1024 + q];
    const u16x8 v =
        *(const u16x8*)(Opart + (size_t)(zb + s) * 1310720 + (size_t)q * 1280 + c);
#pragma unroll
    for (int j = 0; j < 8; ++j) acc[j] += bf2f(v[j]);
  }
  const float rl = 1.0f / L;
  u16x8 o8;
#pragma unroll
  for (int j = 0; j < 8; ++j) o8[j] = f2bf(acc[j] * rl);
  *(u16x8*)(attnb + (size_t)row * 1280 + c) = o8;
}

// ---------------------------------------------------------------------------
extern "C" void kernel_launch(void* const* d_in, const int* in_sizes, int n_in,
                              void* d_out, int out_size, void* d_ws,
                              size_t ws_size, hipStream_t stream) {
  const float* X = (const float*)d_in[0];
  const float* Wq = (const float*)d_in[1];
  const float* Wk = (const float*)d_in[2];
  const float* Wv = (const float*)d_in[3];
  const float* Wo = (const float*)d_in[4];
  const float* bo = (const float*)d_in[5];
  float* out = (float*)d_out;

  char* ws = (char*)d_ws;
  size_t off = 0;
  auto alloc = [&](size_t bytes) {
    char* p = ws + off;
    off += (bytes + 255) & ~(size_t)255;
    return p;
  };
  unsigned short* Wcat = (unsigned short*)alloc(3840ull * 1280 * 2);
  unsigned short* Xbf = (unsigned short*)alloc(4096ull * 1280 * 2);
  unsigned short* QKV = (unsigned short*)alloc(4096ull * 3840 * 2);
  unsigned short* Wobf = (unsigned short*)alloc(1280ull * 1280 * 2);
  float* stats = (float*)alloc(2ull * 2 * 4 * 1280 * 4);
  unsigned short* qnb = (unsigned short*)alloc(4096ull * 1280 * 2);
  unsigned short* knb = (unsigned short*)alloc(4096ull * 1280 * 2);
  unsigned short* vtb = (unsigned short*)alloc(4096ull * 1280 * 2);
  unsigned short* attnb = (unsigned short*)alloc(4096ull * 1280 * 2);

  unsigned short* Opart = QKV;                        // 12 x 1024 x 1280 bf16
  float* Lpart = (float*)Wcat;                        // 12 x 20 x 1024 fp32
  float* psum = (float*)attnb;                        // 8 x 32 x 1280 fp32
  float* psq = (float*)(attnb + 4096ull * 1280 / 2);  // second half

  k_convert_all<<<11520, BDIM, 0, stream>>>(X, Wq, Wk, Wv, Wo, Xbf, Wcat, Wobf);
  k_gemm_bf16<<<dim3(32, 30), BDIM, 0, stream>>>(Xbf, Wcat, QKV, 4096, 3840,
                                                 1280);
  k_stats1<<<dim3(32, 8), 320, 0, stream>>>(QKV, psum, psq);
  k_stats2<<<dim3(5, 8), BDIM, 0, stream>>>(psum, psq, stats);
  k_adain_vt<<<11520, BDIM, 0, stream>>>(QKV, stats, qnb, knb, vtb);
  k_attn<<<dim3(8, 20, 12), BDIM, 0, stream>>>(qnb, knb, vtb, Opart, Lpart);
  k_combine<<<2560, BDIM, 0, stream>>>(Opart, Lpart, attnb);
  k_gemm_64x128<<<dim3(64, 10), BDIM, 0, stream>>>(attnb, Wobf, out, bo, 4096,
                                                   1280, 1280);
}